// Round 5
// baseline (645.265 us; speedup 1.0000x reference)
//
#include <hip/hip_runtime.h>

// ---------------------------------------------------------------------------
// GAT encoder, 2 layers, N=100K nodes, E=1.6M edges (+N self loops), F=128,
// heads=2 x 64ch.
//   1. dst-CSR built once (vectorized histogram -> scan -> scatter).
//   2. Per layer: fp32 GEMM h = x@W (64-row tiles, W in LDS quarters, 8x4
//      register blocking) with fused alpha epilogue; then per-node wave
//      aggregation: lane c owns channels (2c,2c+1) -> single float2 gather
//      per edge, 8-deep pipelined, nontemporal output stores.
//   Softmax max-subtraction skipped (logits bounded, exp safe in fp32).
// ---------------------------------------------------------------------------

typedef float f32x2 __attribute__((ext_vector_type(2)));

__global__ __launch_bounds__(256) void k_hist(const int* __restrict__ ei,
                                              int* __restrict__ deg, int E, int n) {
    int i = blockIdx.x * blockDim.x + threadIdx.x;
    int E4 = E >> 2;
    if (i < E4) {
        int4 d4 = ((const int4*)(ei + E))[i];
        atomicAdd(&deg[d4.x], 1);
        atomicAdd(&deg[d4.y], 1);
        atomicAdd(&deg[d4.z], 1);
        atomicAdd(&deg[d4.w], 1);
    } else if (i < E4 + n) {
        atomicAdd(&deg[i - E4], 1);             // self loop
    }
    // tail edges (E not multiple of 4)
    int tail = E & 3;
    if (i < tail) atomicAdd(&deg[ei[E + (E4 << 2) + i]], 1);
}

__global__ __launch_bounds__(1024) void k_scan_block(const int* __restrict__ deg,
                                                     int* __restrict__ off,
                                                     int* __restrict__ bsum, int n) {
    __shared__ int tmp[1024];
    int t = threadIdx.x;
    int i = blockIdx.x * 1024 + t;
    int v = (i < n) ? deg[i] : 0;
    tmp[t] = v;
    __syncthreads();
    for (int d = 1; d < 1024; d <<= 1) {
        int a = (t >= d) ? tmp[t - d] : 0;
        __syncthreads();
        tmp[t] += a;
        __syncthreads();
    }
    if (i < n) off[i] = tmp[t] - v;             // exclusive
    if (t == 1023) bsum[blockIdx.x] = tmp[t];
}

__global__ __launch_bounds__(128) void k_scan_bsum(int* __restrict__ bsum, int nb) {
    __shared__ int tmp[128];
    int t = threadIdx.x;
    int v = (t < nb) ? bsum[t] : 0;
    tmp[t] = v;
    __syncthreads();
    for (int d = 1; d < 128; d <<= 1) {
        int a = (t >= d) ? tmp[t - d] : 0;
        __syncthreads();
        tmp[t] += a;
        __syncthreads();
    }
    if (t < nb) bsum[t] = tmp[t] - v;           // exclusive over block sums
}

__global__ __launch_bounds__(1024) void k_scan_add(int* __restrict__ off,
                                                   const int* __restrict__ bsum, int n) {
    int i = blockIdx.x * 1024 + threadIdx.x;
    if (i < n) off[i] += bsum[blockIdx.x];
}

__global__ __launch_bounds__(256) void k_scatter(const int* __restrict__ ei,
                                                 const int* __restrict__ off,
                                                 int* __restrict__ cursor,
                                                 int* __restrict__ csr, int E, int n) {
    int i = blockIdx.x * blockDim.x + threadIdx.x;
    if (i < E) {
        int d = ei[E + i];
        int p = atomicAdd(&cursor[d], 1);
        csr[off[d] + p] = ei[i];
    } else if (i < E + n) {
        int nn = i - E;
        int p = atomicAdd(&cursor[nn], 1);
        csr[off[nn] + p] = nn;
    }
}

// GEMM: H[row,col] = sum_k X[row,k]*W[k,col]. 64-row X tile in LDS (32 KB),
// W staged in four 32-row quarters (16 KB), acc[8 rows][4 cols] per thread.
// Thread t: rgrp=t>>5 owns rows rgrp*8..+7; c32=t&31 owns cols 4c32..+3.
__global__ __launch_bounds__(256) void k_gemm_alpha(
    const float* __restrict__ X, const float* __restrict__ W,
    const float* __restrict__ a_src, const float* __restrict__ a_dst,
    float* __restrict__ H, float* __restrict__ as_out, float* __restrict__ ad_out,
    int n) {
    __shared__ float xs[64 * 128];   // 32 KB
    __shared__ float ws[32 * 128];   // 16 KB (one W quarter)
    int t = threadIdx.x;
    int rowBase = blockIdx.x * 64;
    const float4* X4 = (const float4*)X;
    const float4* W4 = (const float4*)W;

    // stage X tile (64 rows x 128 = 2048 float4)
#pragma unroll
    for (int it = 0; it < 8; ++it) {
        int idx = t + it * 256;
        int row = rowBase + (idx >> 5);
        float4 v = make_float4(0.f, 0.f, 0.f, 0.f);
        if (row < n) v = X4[(size_t)row * 32 + (idx & 31)];
        ((float4*)xs)[idx] = v;
    }

    int rgrp = t >> 5, c32 = t & 31;
    float4 acc[8];
#pragma unroll
    for (int i = 0; i < 8; ++i) acc[i] = make_float4(0.f, 0.f, 0.f, 0.f);

    const float4* xs4 = (const float4*)xs;
    const float4* ws4 = (const float4*)ws;

    for (int q = 0; q < 4; ++q) {
        if (q > 0) __syncthreads();             // compute(q-1) done before restage
#pragma unroll
        for (int it = 0; it < 4; ++it)
            ((float4*)ws)[t + it * 256] = W4[q * 1024 + t + it * 256];
        __syncthreads();
#pragma unroll 2
        for (int k4 = 0; k4 < 8; ++k4) {
            float4 xv[8];
#pragma unroll
            for (int i = 0; i < 8; ++i)
                xv[i] = xs4[(rgrp * 8 + i) * 32 + q * 8 + k4];
#pragma unroll
            for (int kk = 0; kk < 4; ++kk) {
                float4 w = ws4[(k4 * 4 + kk) * 32 + c32];
#pragma unroll
                for (int i = 0; i < 8; ++i) {
                    float xk = (&xv[i].x)[kk];
                    acc[i].x += xk * w.x; acc[i].y += xk * w.y;
                    acc[i].z += xk * w.z; acc[i].w += xk * w.w;
                }
            }
        }
    }

    // epilogue: store H rows + fused alpha reductions
    float4 as4 = ((const float4*)a_src)[c32];
    float4 ad4 = ((const float4*)a_dst)[c32];
#pragma unroll
    for (int i = 0; i < 8; ++i) {
        int row = rowBase + rgrp * 8 + i;
        if (row >= n) continue;
        ((float4*)(H + (size_t)row * 128))[c32] = acc[i];
        float ps = acc[i].x * as4.x + acc[i].y * as4.y + acc[i].z * as4.z + acc[i].w * as4.w;
        float pd = acc[i].x * ad4.x + acc[i].y * ad4.y + acc[i].z * ad4.z + acc[i].w * ad4.w;
#pragma unroll
        for (int m = 8; m >= 1; m >>= 1) {
            ps += __shfl_xor(ps, m, 16);
            pd += __shfl_xor(pd, m, 16);
        }
        if ((c32 & 15) == 0) {
            int head = c32 >> 4;
            as_out[row * 2 + head] = ps;
            ad_out[row * 2 + head] = pd;
        }
    }
}

// Aggregation: one wave per node. Lane c owns channels (2c, 2c+1); head=c>>5.
// Single float2 gather per edge per lane; per-lane head-specific weight.
__global__ __launch_bounds__(256) void k_agg(
    const float* __restrict__ H, const float* __restrict__ as,
    const float* __restrict__ ad, const float* __restrict__ bias,
    const int* __restrict__ csr, const int* __restrict__ off,
    const int* __restrict__ deg, float* __restrict__ out, int n) {
    int wave = threadIdx.x >> 6, lane = threadIdx.x & 63;
    int node = blockIdx.x * 4 + wave;
    if (node >= n) return;
    int o = off[node], d = deg[node];
    int head = lane >> 5;
    float adh = ad[node * 2 + head];
    const float* Hl = H + 2 * lane;            // lane-fixed channel offset
    const float* ash = as + head;
    float acc0 = 0.f, acc1 = 0.f, den = 0.f;
    int j = 0;
    for (; j + 8 <= d; j += 8) {
        int s0 = csr[o + j],     s1 = csr[o + j + 1];
        int s2 = csr[o + j + 2], s3 = csr[o + j + 3];
        int s4 = csr[o + j + 4], s5 = csr[o + j + 5];
        int s6 = csr[o + j + 6], s7 = csr[o + j + 7];
        float a0 = ash[s0 * 2], a1 = ash[s1 * 2], a2 = ash[s2 * 2], a3 = ash[s3 * 2];
        float a4 = ash[s4 * 2], a5 = ash[s5 * 2], a6 = ash[s6 * 2], a7 = ash[s7 * 2];
        f32x2 g0 = *(const f32x2*)(Hl + (size_t)s0 * 128);
        f32x2 g1 = *(const f32x2*)(Hl + (size_t)s1 * 128);
        f32x2 g2 = *(const f32x2*)(Hl + (size_t)s2 * 128);
        f32x2 g3 = *(const f32x2*)(Hl + (size_t)s3 * 128);
        f32x2 g4 = *(const f32x2*)(Hl + (size_t)s4 * 128);
        f32x2 g5 = *(const f32x2*)(Hl + (size_t)s5 * 128);
        f32x2 g6 = *(const f32x2*)(Hl + (size_t)s6 * 128);
        f32x2 g7 = *(const f32x2*)(Hl + (size_t)s7 * 128);
        float e, w;
        e = a0 + adh; e = fmaxf(e, 0.2f * e); w = __expf(e);
        den += w; acc0 += w * g0.x; acc1 += w * g0.y;
        e = a1 + adh; e = fmaxf(e, 0.2f * e); w = __expf(e);
        den += w; acc0 += w * g1.x; acc1 += w * g1.y;
        e = a2 + adh; e = fmaxf(e, 0.2f * e); w = __expf(e);
        den += w; acc0 += w * g2.x; acc1 += w * g2.y;
        e = a3 + adh; e = fmaxf(e, 0.2f * e); w = __expf(e);
        den += w; acc0 += w * g3.x; acc1 += w * g3.y;
        e = a4 + adh; e = fmaxf(e, 0.2f * e); w = __expf(e);
        den += w; acc0 += w * g4.x; acc1 += w * g4.y;
        e = a5 + adh; e = fmaxf(e, 0.2f * e); w = __expf(e);
        den += w; acc0 += w * g5.x; acc1 += w * g5.y;
        e = a6 + adh; e = fmaxf(e, 0.2f * e); w = __expf(e);
        den += w; acc0 += w * g6.x; acc1 += w * g6.y;
        e = a7 + adh; e = fmaxf(e, 0.2f * e); w = __expf(e);
        den += w; acc0 += w * g7.x; acc1 += w * g7.y;
    }
    for (; j < d; ++j) {
        int s = csr[o + j];
        float a = ash[s * 2];
        f32x2 g = *(const f32x2*)(Hl + (size_t)s * 128);
        float e = a + adh; e = fmaxf(e, 0.2f * e);
        float w = __expf(e);
        den += w; acc0 += w * g.x; acc1 += w * g.y;
    }
    f32x2 b2 = *(const f32x2*)(bias + 2 * lane);
    float inv = 1.f / den;
    float r0 = acc0 * inv + b2.x;
    float r1 = acc1 * inv + b2.y;
    r0 = r0 > 0.f ? r0 : __expf(r0) - 1.f;   // ELU
    r1 = r1 > 0.f ? r1 : __expf(r1) - 1.f;
    f32x2 r; r.x = r0; r.y = r1;
    __builtin_nontemporal_store(r, (f32x2*)(out + (size_t)node * 128 + 2 * lane));
}

extern "C" void kernel_launch(void* const* d_in, const int* in_sizes, int n_in,
                              void* d_out, int out_size, void* d_ws, size_t ws_size,
                              hipStream_t stream) {
    const float* x   = (const float*)d_in[0];
    const int*   ei  = (const int*)d_in[1];
    const float* W1  = (const float*)d_in[2];
    const float* as1 = (const float*)d_in[3];
    const float* ad1 = (const float*)d_in[4];
    const float* b1  = (const float*)d_in[5];
    const float* W2  = (const float*)d_in[6];
    const float* as2 = (const float*)d_in[7];
    const float* ad2 = (const float*)d_in[8];
    const float* b2  = (const float*)d_in[9];

    const int N = in_sizes[0] / 128;
    const int E = in_sizes[1] / 2;

    // workspace carve-up
    float* h       = (float*)d_ws;                 // N*128
    float* y1      = h + (size_t)N * 128;          // N*128
    float* alpha_s = y1 + (size_t)N * 128;         // 2N
    float* alpha_d = alpha_s + 2 * (size_t)N;      // 2N
    int*   deg     = (int*)(alpha_d + 2 * (size_t)N);
    int*   off     = deg + N;
    int*   cursor  = off + N;
    int*   bsum    = cursor + N;                   // 128
    int*   csr     = bsum + 128;                   // E+N

    hipMemsetAsync(deg, 0, (size_t)N * 4, stream);
    hipMemsetAsync(cursor, 0, (size_t)N * 4, stream);

    int nb = (N + 1023) / 1024;
    k_hist<<<((E >> 2) + N + 255) / 256, 256, 0, stream>>>(ei, deg, E, N);
    k_scan_block<<<nb, 1024, 0, stream>>>(deg, off, bsum, N);
    k_scan_bsum<<<1, 128, 0, stream>>>(bsum, nb);
    k_scan_add<<<nb, 1024, 0, stream>>>(off, bsum, N);
    k_scatter<<<(E + N + 255) / 256, 256, 0, stream>>>(ei, off, cursor, csr, E, N);

    // layer 1
    k_gemm_alpha<<<(N + 63) / 64, 256, 0, stream>>>(x, W1, as1, ad1, h, alpha_s, alpha_d, N);
    k_agg<<<(N + 3) / 4, 256, 0, stream>>>(h, alpha_s, alpha_d, b1, csr, off, deg, y1, N);

    // layer 2
    k_gemm_alpha<<<(N + 63) / 64, 256, 0, stream>>>(y1, W2, as2, ad2, h, alpha_s, alpha_d, N);
    k_agg<<<(N + 3) / 4, 256, 0, stream>>>(h, alpha_s, alpha_d, b2, csr, off, deg, (float*)d_out, N);
}

// Round 6
// 502.164 us; speedup vs baseline: 1.2850x; 1.2850x over previous
//
#include <hip/hip_runtime.h>

// ---------------------------------------------------------------------------
// GAT encoder, 2 layers, N=100K nodes, E=1.6M edges (+N self loops), F=128,
// heads=2 x 64ch.
//   1. dst-CSR built once: hist (atomicAdd returns slot) -> scan -> atomic-free
//      scatter. pos[] scratch aliases the y1 buffer (written only later).
//   2. Per layer: fp32 GEMM h = x@W (64-row tiles, W in LDS quarters, 8x4
//      register blocking), H stored as fp16 (only the gather reads it),
//      alpha_src/alpha_dst fused into the epilogue in fp32; then per-node
//      wave aggregation: lane c owns channels (2c,2c+1) -> single 4-byte
//      half2 gather per edge, 8-deep pipelined, NT output stores.
//   Softmax max-subtraction skipped (logits bounded, exp safe in fp32).
// ---------------------------------------------------------------------------

typedef float  f32x2 __attribute__((ext_vector_type(2)));
typedef __fp16 f16x2 __attribute__((ext_vector_type(2)));
typedef __fp16 f16x4 __attribute__((ext_vector_type(4)));

__global__ __launch_bounds__(256) void k_hist(const int* __restrict__ ei,
                                              int* __restrict__ deg,
                                              int* __restrict__ pos,
                                              int* __restrict__ pos_self,
                                              int E, int n) {
    int i = blockIdx.x * blockDim.x + threadIdx.x;
    if (i < E) {
        pos[i] = atomicAdd(&deg[ei[E + i]], 1);
    } else if (i < E + n) {
        int nn = i - E;
        pos_self[nn] = atomicAdd(&deg[nn], 1);
    }
}

__global__ __launch_bounds__(1024) void k_scan_block(const int* __restrict__ deg,
                                                     int* __restrict__ off,
                                                     int* __restrict__ bsum, int n) {
    __shared__ int tmp[1024];
    int t = threadIdx.x;
    int i = blockIdx.x * 1024 + t;
    int v = (i < n) ? deg[i] : 0;
    tmp[t] = v;
    __syncthreads();
    for (int d = 1; d < 1024; d <<= 1) {
        int a = (t >= d) ? tmp[t - d] : 0;
        __syncthreads();
        tmp[t] += a;
        __syncthreads();
    }
    if (i < n) off[i] = tmp[t] - v;             // exclusive
    if (t == 1023) bsum[blockIdx.x] = tmp[t];
}

__global__ __launch_bounds__(128) void k_scan_bsum(int* __restrict__ bsum, int nb) {
    __shared__ int tmp[128];
    int t = threadIdx.x;
    int v = (t < nb) ? bsum[t] : 0;
    tmp[t] = v;
    __syncthreads();
    for (int d = 1; d < 128; d <<= 1) {
        int a = (t >= d) ? tmp[t - d] : 0;
        __syncthreads();
        tmp[t] += a;
        __syncthreads();
    }
    if (t < nb) bsum[t] = tmp[t] - v;           // exclusive over block sums
}

__global__ __launch_bounds__(1024) void k_scan_add(int* __restrict__ off,
                                                   const int* __restrict__ bsum, int n) {
    int i = blockIdx.x * 1024 + threadIdx.x;
    if (i < n) off[i] += bsum[blockIdx.x];
}

// atomic-free scatter using hist-provided slots
__global__ __launch_bounds__(256) void k_scatter(const int* __restrict__ ei,
                                                 const int* __restrict__ off,
                                                 const int* __restrict__ pos,
                                                 const int* __restrict__ pos_self,
                                                 int* __restrict__ csr, int E, int n) {
    int i = blockIdx.x * blockDim.x + threadIdx.x;
    if (i < E) {
        int d = ei[E + i];
        csr[off[d] + pos[i]] = ei[i];
    } else if (i < E + n) {
        int nn = i - E;
        csr[off[nn] + pos_self[nn]] = nn;
    }
}

// GEMM: H[row,col] = sum_k X[row,k]*W[k,col]. 64-row X tile in LDS (32 KB),
// W staged in four 32-row quarters (16 KB), acc[8 rows][4 cols] per thread.
// H stored as fp16 (gather-only consumer). Alphas computed in fp32.
__global__ __launch_bounds__(256) void k_gemm_alpha(
    const float* __restrict__ X, const float* __restrict__ W,
    const float* __restrict__ a_src, const float* __restrict__ a_dst,
    __fp16* __restrict__ Hh, float* __restrict__ as_out, float* __restrict__ ad_out,
    int n) {
    __shared__ float xs[64 * 128];   // 32 KB
    __shared__ float ws[32 * 128];   // 16 KB (one W quarter)
    int t = threadIdx.x;
    int rowBase = blockIdx.x * 64;
    const float4* X4 = (const float4*)X;
    const float4* W4 = (const float4*)W;

    // stage X tile (64 rows x 128 = 2048 float4)
#pragma unroll
    for (int it = 0; it < 8; ++it) {
        int idx = t + it * 256;
        int row = rowBase + (idx >> 5);
        float4 v = make_float4(0.f, 0.f, 0.f, 0.f);
        if (row < n) v = X4[(size_t)row * 32 + (idx & 31)];
        ((float4*)xs)[idx] = v;
    }

    int rgrp = t >> 5, c32 = t & 31;
    float4 acc[8];
#pragma unroll
    for (int i = 0; i < 8; ++i) acc[i] = make_float4(0.f, 0.f, 0.f, 0.f);

    const float4* xs4 = (const float4*)xs;
    const float4* ws4 = (const float4*)ws;

    for (int q = 0; q < 4; ++q) {
        if (q > 0) __syncthreads();             // compute(q-1) done before restage
#pragma unroll
        for (int it = 0; it < 4; ++it)
            ((float4*)ws)[t + it * 256] = W4[q * 1024 + t + it * 256];
        __syncthreads();
#pragma unroll 2
        for (int k4 = 0; k4 < 8; ++k4) {
            float4 xv[8];
#pragma unroll
            for (int i = 0; i < 8; ++i)
                xv[i] = xs4[(rgrp * 8 + i) * 32 + q * 8 + k4];
#pragma unroll
            for (int kk = 0; kk < 4; ++kk) {
                float4 w = ws4[(k4 * 4 + kk) * 32 + c32];
#pragma unroll
                for (int i = 0; i < 8; ++i) {
                    float xk = (&xv[i].x)[kk];
                    acc[i].x += xk * w.x; acc[i].y += xk * w.y;
                    acc[i].z += xk * w.z; acc[i].w += xk * w.w;
                }
            }
        }
    }

    // epilogue: store fp16 H rows + fused fp32 alpha reductions
    float4 as4 = ((const float4*)a_src)[c32];
    float4 ad4 = ((const float4*)a_dst)[c32];
#pragma unroll
    for (int i = 0; i < 8; ++i) {
        int row = rowBase + rgrp * 8 + i;
        if (row >= n) continue;
        f16x4 hv;
        hv.x = (__fp16)acc[i].x; hv.y = (__fp16)acc[i].y;
        hv.z = (__fp16)acc[i].z; hv.w = (__fp16)acc[i].w;
        *(f16x4*)(Hh + (size_t)row * 128 + 4 * c32) = hv;
        float ps = acc[i].x * as4.x + acc[i].y * as4.y + acc[i].z * as4.z + acc[i].w * as4.w;
        float pd = acc[i].x * ad4.x + acc[i].y * ad4.y + acc[i].z * ad4.z + acc[i].w * ad4.w;
#pragma unroll
        for (int m = 8; m >= 1; m >>= 1) {
            ps += __shfl_xor(ps, m, 16);
            pd += __shfl_xor(pd, m, 16);
        }
        if ((c32 & 15) == 0) {
            int head = c32 >> 4;
            as_out[row * 2 + head] = ps;
            ad_out[row * 2 + head] = pd;
        }
    }
}

// Aggregation: one wave per node. Lane c owns channels (2c, 2c+1); head=c>>5.
// Single 4-byte half2 gather per edge per lane; fp32 weights/accumulators.
__global__ __launch_bounds__(256) void k_agg(
    const __fp16* __restrict__ Hh, const float* __restrict__ as,
    const float* __restrict__ ad, const float* __restrict__ bias,
    const int* __restrict__ csr, const int* __restrict__ off,
    const int* __restrict__ deg, float* __restrict__ out, int n) {
    int wave = threadIdx.x >> 6, lane = threadIdx.x & 63;
    int node = blockIdx.x * 4 + wave;
    if (node >= n) return;
    int o = off[node], d = deg[node];
    int head = lane >> 5;
    float adh = ad[node * 2 + head];
    const __fp16* Hl = Hh + 2 * lane;          // lane-fixed channel offset
    const float* ash = as + head;
    float acc0 = 0.f, acc1 = 0.f, den = 0.f;
    int j = 0;
    for (; j + 8 <= d; j += 8) {
        int s0 = csr[o + j],     s1 = csr[o + j + 1];
        int s2 = csr[o + j + 2], s3 = csr[o + j + 3];
        int s4 = csr[o + j + 4], s5 = csr[o + j + 5];
        int s6 = csr[o + j + 6], s7 = csr[o + j + 7];
        float a0 = ash[s0 * 2], a1 = ash[s1 * 2], a2 = ash[s2 * 2], a3 = ash[s3 * 2];
        float a4 = ash[s4 * 2], a5 = ash[s5 * 2], a6 = ash[s6 * 2], a7 = ash[s7 * 2];
        f16x2 g0 = *(const f16x2*)(Hl + (size_t)s0 * 128);
        f16x2 g1 = *(const f16x2*)(Hl + (size_t)s1 * 128);
        f16x2 g2 = *(const f16x2*)(Hl + (size_t)s2 * 128);
        f16x2 g3 = *(const f16x2*)(Hl + (size_t)s3 * 128);
        f16x2 g4 = *(const f16x2*)(Hl + (size_t)s4 * 128);
        f16x2 g5 = *(const f16x2*)(Hl + (size_t)s5 * 128);
        f16x2 g6 = *(const f16x2*)(Hl + (size_t)s6 * 128);
        f16x2 g7 = *(const f16x2*)(Hl + (size_t)s7 * 128);
        float e, w;
        e = a0 + adh; e = fmaxf(e, 0.2f * e); w = __expf(e);
        den += w; acc0 += w * (float)g0.x; acc1 += w * (float)g0.y;
        e = a1 + adh; e = fmaxf(e, 0.2f * e); w = __expf(e);
        den += w; acc0 += w * (float)g1.x; acc1 += w * (float)g1.y;
        e = a2 + adh; e = fmaxf(e, 0.2f * e); w = __expf(e);
        den += w; acc0 += w * (float)g2.x; acc1 += w * (float)g2.y;
        e = a3 + adh; e = fmaxf(e, 0.2f * e); w = __expf(e);
        den += w; acc0 += w * (float)g3.x; acc1 += w * (float)g3.y;
        e = a4 + adh; e = fmaxf(e, 0.2f * e); w = __expf(e);
        den += w; acc0 += w * (float)g4.x; acc1 += w * (float)g4.y;
        e = a5 + adh; e = fmaxf(e, 0.2f * e); w = __expf(e);
        den += w; acc0 += w * (float)g5.x; acc1 += w * (float)g5.y;
        e = a6 + adh; e = fmaxf(e, 0.2f * e); w = __expf(e);
        den += w; acc0 += w * (float)g6.x; acc1 += w * (float)g6.y;
        e = a7 + adh; e = fmaxf(e, 0.2f * e); w = __expf(e);
        den += w; acc0 += w * (float)g7.x; acc1 += w * (float)g7.y;
    }
    for (; j < d; ++j) {
        int s = csr[o + j];
        float a = ash[s * 2];
        f16x2 g = *(const f16x2*)(Hl + (size_t)s * 128);
        float e = a + adh; e = fmaxf(e, 0.2f * e);
        float w = __expf(e);
        den += w; acc0 += w * (float)g.x; acc1 += w * (float)g.y;
    }
    f32x2 b2 = *(const f32x2*)(bias + 2 * lane);
    float inv = 1.f / den;
    float r0 = acc0 * inv + b2.x;
    float r1 = acc1 * inv + b2.y;
    r0 = r0 > 0.f ? r0 : __expf(r0) - 1.f;   // ELU
    r1 = r1 > 0.f ? r1 : __expf(r1) - 1.f;
    f32x2 r; r.x = r0; r.y = r1;
    __builtin_nontemporal_store(r, (f32x2*)(out + (size_t)node * 128 + 2 * lane));
}

extern "C" void kernel_launch(void* const* d_in, const int* in_sizes, int n_in,
                              void* d_out, int out_size, void* d_ws, size_t ws_size,
                              hipStream_t stream) {
    const float* x   = (const float*)d_in[0];
    const int*   ei  = (const int*)d_in[1];
    const float* W1  = (const float*)d_in[2];
    const float* as1 = (const float*)d_in[3];
    const float* ad1 = (const float*)d_in[4];
    const float* b1  = (const float*)d_in[5];
    const float* W2  = (const float*)d_in[6];
    const float* as2 = (const float*)d_in[7];
    const float* ad2 = (const float*)d_in[8];
    const float* b2  = (const float*)d_in[9];

    const int N = in_sizes[0] / 128;
    const int E = in_sizes[1] / 2;

    // workspace carve-up
    __fp16* Hh     = (__fp16*)d_ws;                         // N*128 fp16
    float*  y1     = (float*)(Hh + (size_t)N * 128);        // N*128 fp32
    float*  alpha_s = y1 + (size_t)N * 128;                 // 2N
    float*  alpha_d = alpha_s + 2 * (size_t)N;              // 2N
    int*    deg    = (int*)(alpha_d + 2 * (size_t)N);
    int*    off    = deg + N;
    int*    bsum   = off + N;                               // 128
    int*    csr    = bsum + 128;                            // E+N
    // pos/pos_self alias y1: only live between k_hist and k_scatter,
    // both of which complete before layer-1 k_agg writes y1.
    int*    pos      = (int*)y1;                            // E
    int*    pos_self = pos + E;                             // N

    hipMemsetAsync(deg, 0, (size_t)N * 4, stream);

    int nb = (N + 1023) / 1024;
    k_hist<<<(E + N + 255) / 256, 256, 0, stream>>>(ei, deg, pos, pos_self, E, N);
    k_scan_block<<<nb, 1024, 0, stream>>>(deg, off, bsum, N);
    k_scan_bsum<<<1, 128, 0, stream>>>(bsum, nb);
    k_scan_add<<<nb, 1024, 0, stream>>>(off, bsum, N);
    k_scatter<<<(E + N + 255) / 256, 256, 0, stream>>>(ei, off, pos, pos_self, csr, E, N);

    // layer 1
    k_gemm_alpha<<<(N + 63) / 64, 256, 0, stream>>>(x, W1, as1, ad1, Hh, alpha_s, alpha_d, N);
    k_agg<<<(N + 3) / 4, 256, 0, stream>>>(Hh, alpha_s, alpha_d, b1, csr, off, deg, y1, N);

    // layer 2
    k_gemm_alpha<<<(N + 63) / 64, 256, 0, stream>>>(y1, W2, as2, ad2, Hh, alpha_s, alpha_d, N);
    k_agg<<<(N + 3) / 4, 256, 0, stream>>>(Hh, alpha_s, alpha_d, b2, csr, off, deg, (float*)d_out, N);
}

// Round 7
// 483.832 us; speedup vs baseline: 1.3337x; 1.0379x over previous
//
#include <hip/hip_runtime.h>

// ---------------------------------------------------------------------------
// GAT encoder, 2 layers, N=100K nodes, E=1.6M edges (+N self loops), F=128,
// heads=2 x 64ch.
//   1. dst-CSR built once: vectorized hist (atomicAdd returns slot) -> scan ->
//      atomic-free vectorized scatter. pos[] aliases the y1 buffer.
//   2. Per layer: GEMM h = x@W via v_dot2_f32_f16 (fp16 inputs, fp32 accum;
//      X tile + full W in LDS as fp16 k-pairs, one sync), H stored fp16,
//      alpha_src/alpha_dst fused fp32 epilogue; then per-node wave
//      aggregation: lane c owns channels (2c,2c+1) -> single 4-byte gather
//      per edge, 8-deep pipelined, NT output stores. y1 kept fp32 for margin.
//   Softmax max-subtraction skipped (logits bounded, exp safe in fp32).
// ---------------------------------------------------------------------------

typedef float    f32x2 __attribute__((ext_vector_type(2)));
typedef _Float16 h2v   __attribute__((ext_vector_type(2)));
typedef _Float16 h4v   __attribute__((ext_vector_type(4)));
typedef _Float16 h8v   __attribute__((ext_vector_type(8)));

#if __has_builtin(__builtin_amdgcn_fdot2)
#define FDOT2(a, b, c) __builtin_amdgcn_fdot2((a), (b), (c), false)
#else
#define FDOT2(a, b, c) ((c) + (float)(a).x * (float)(b).x + (float)(a).y * (float)(b).y)
#endif

__global__ __launch_bounds__(256) void k_hist(const int* __restrict__ ei,
                                              int* __restrict__ deg,
                                              int* __restrict__ pos,
                                              int* __restrict__ pos_self,
                                              int E, int n) {
    int i = blockIdx.x * blockDim.x + threadIdx.x;
    int E4 = E >> 2;
    if (i < E4) {
        int4 d4 = ((const int4*)(ei + E))[i];
        int4 p;
        p.x = atomicAdd(&deg[d4.x], 1);
        p.y = atomicAdd(&deg[d4.y], 1);
        p.z = atomicAdd(&deg[d4.z], 1);
        p.w = atomicAdd(&deg[d4.w], 1);
        ((int4*)pos)[i] = p;
    } else if (i < E4 + n) {
        int nn = i - E4;
        pos_self[nn] = atomicAdd(&deg[nn], 1);
    }
    int tail = E & 3;
    if (i < tail) {
        int e = (E4 << 2) + i;
        pos[e] = atomicAdd(&deg[ei[E + e]], 1);
    }
}

__global__ __launch_bounds__(1024) void k_scan_block(const int* __restrict__ deg,
                                                     int* __restrict__ off,
                                                     int* __restrict__ bsum, int n) {
    __shared__ int tmp[1024];
    int t = threadIdx.x;
    int i = blockIdx.x * 1024 + t;
    int v = (i < n) ? deg[i] : 0;
    tmp[t] = v;
    __syncthreads();
    for (int d = 1; d < 1024; d <<= 1) {
        int a = (t >= d) ? tmp[t - d] : 0;
        __syncthreads();
        tmp[t] += a;
        __syncthreads();
    }
    if (i < n) off[i] = tmp[t] - v;             // exclusive
    if (t == 1023) bsum[blockIdx.x] = tmp[t];
}

__global__ __launch_bounds__(128) void k_scan_bsum(int* __restrict__ bsum, int nb) {
    __shared__ int tmp[128];
    int t = threadIdx.x;
    int v = (t < nb) ? bsum[t] : 0;
    tmp[t] = v;
    __syncthreads();
    for (int d = 1; d < 128; d <<= 1) {
        int a = (t >= d) ? tmp[t - d] : 0;
        __syncthreads();
        tmp[t] += a;
        __syncthreads();
    }
    if (t < nb) bsum[t] = tmp[t] - v;           // exclusive over block sums
}

__global__ __launch_bounds__(1024) void k_scan_add(int* __restrict__ off,
                                                   const int* __restrict__ bsum, int n) {
    int i = blockIdx.x * 1024 + threadIdx.x;
    if (i < n) off[i] += bsum[blockIdx.x];
}

// atomic-free scatter using hist-provided slots, 4 edges/thread
__global__ __launch_bounds__(256) void k_scatter(const int* __restrict__ ei,
                                                 const int* __restrict__ off,
                                                 const int* __restrict__ pos,
                                                 const int* __restrict__ pos_self,
                                                 int* __restrict__ csr, int E, int n) {
    int i = blockIdx.x * blockDim.x + threadIdx.x;
    int E4 = E >> 2;
    if (i < E4) {
        int4 s4 = ((const int4*)ei)[i];
        int4 d4 = ((const int4*)(ei + E))[i];
        int4 p4 = ((const int4*)pos)[i];
        csr[off[d4.x] + p4.x] = s4.x;
        csr[off[d4.y] + p4.y] = s4.y;
        csr[off[d4.z] + p4.z] = s4.z;
        csr[off[d4.w] + p4.w] = s4.w;
    } else if (i < E4 + n) {
        int nn = i - E4;
        csr[off[nn] + pos_self[nn]] = nn;
    }
    int tail = E & 3;
    if (i < tail) {
        int e = (E4 << 2) + i;
        int d = ei[E + e];
        csr[off[d] + pos[e]] = ei[e];
    }
}

// GEMM via fdot2: H[row,col] = sum_k X[row,k]*W[k,col], fp16 inputs, fp32 acc.
// LDS: xs[64 rows][64 k-pairs] (16 KB), ws[64 k-pairs][128 cols] (32 KB, all
// of W, k-pair interleaved: ws[kk][c] = (W[2kk][c], W[2kk+1][c])). One sync.
// Thread t: rgrp=t>>5 owns rows rgrp*8..+7; c32=t&31 owns cols 4c32..+3.
__global__ __launch_bounds__(256) void k_gemm_alpha(
    const float* __restrict__ X, const float* __restrict__ W,
    const float* __restrict__ a_src, const float* __restrict__ a_dst,
    _Float16* __restrict__ Hh, float* __restrict__ as_out, float* __restrict__ ad_out,
    int n) {
    __shared__ h2v xs[64 * 64];      // 16 KB  [row][kk]
    __shared__ h2v ws[64 * 128];     // 32 KB  [kk][col]
    int t = threadIdx.x;
    int rowBase = blockIdx.x * 64;
    const float4* X4 = (const float4*)X;
    const float4* W4 = (const float4*)W;

    // stage X tile: 64 rows x 32 float4 -> fp16 pairs
#pragma unroll
    for (int it = 0; it < 8; ++it) {
        int idx = t + it * 256;                  // 0..2047
        int row = idx >> 5, seg = idx & 31;      // seg = float4 index
        float4 v = make_float4(0.f, 0.f, 0.f, 0.f);
        if (rowBase + row < n) v = X4[(size_t)(rowBase + row) * 32 + seg];
        h4v hv;
        hv.x = (_Float16)v.x; hv.y = (_Float16)v.y;
        hv.z = (_Float16)v.z; hv.w = (_Float16)v.w;
        *(h4v*)(xs + row * 64 + seg * 2) = hv;
    }
    // stage W k-pair interleaved: idx -> kk=idx>>5, seg=idx&31 (4 cols)
#pragma unroll
    for (int it = 0; it < 8; ++it) {
        int idx = t + it * 256;                  // 0..2047
        int kk = idx >> 5, seg = idx & 31;
        float4 wa = W4[(size_t)(2 * kk) * 32 + seg];
        float4 wb = W4[(size_t)(2 * kk + 1) * 32 + seg];
        h8v q;
        q[0] = (_Float16)wa.x; q[1] = (_Float16)wb.x;
        q[2] = (_Float16)wa.y; q[3] = (_Float16)wb.y;
        q[4] = (_Float16)wa.z; q[5] = (_Float16)wb.z;
        q[6] = (_Float16)wa.w; q[7] = (_Float16)wb.w;
        *(h8v*)(ws + kk * 128 + seg * 4) = q;
    }
    __syncthreads();

    int rgrp = t >> 5, c32 = t & 31;
    float4 acc[8];
#pragma unroll
    for (int i = 0; i < 8; ++i) acc[i] = make_float4(0.f, 0.f, 0.f, 0.f);

#pragma unroll 4
    for (int kk = 0; kk < 64; ++kk) {
        h2v w0 = ws[kk * 128 + 4 * c32 + 0];
        h2v w1 = ws[kk * 128 + 4 * c32 + 1];
        h2v w2 = ws[kk * 128 + 4 * c32 + 2];
        h2v w3 = ws[kk * 128 + 4 * c32 + 3];
#pragma unroll
        for (int i = 0; i < 8; ++i) {
            h2v xv = xs[(rgrp * 8 + i) * 64 + kk];
            acc[i].x = FDOT2(xv, w0, acc[i].x);
            acc[i].y = FDOT2(xv, w1, acc[i].y);
            acc[i].z = FDOT2(xv, w2, acc[i].z);
            acc[i].w = FDOT2(xv, w3, acc[i].w);
        }
    }

    // epilogue: fp16 H store + fused fp32 alpha reductions
    float4 as4 = ((const float4*)a_src)[c32];
    float4 ad4 = ((const float4*)a_dst)[c32];
#pragma unroll
    for (int i = 0; i < 8; ++i) {
        int row = rowBase + rgrp * 8 + i;
        if (row >= n) continue;
        h4v hv;
        hv.x = (_Float16)acc[i].x; hv.y = (_Float16)acc[i].y;
        hv.z = (_Float16)acc[i].z; hv.w = (_Float16)acc[i].w;
        *(h4v*)(Hh + (size_t)row * 128 + 4 * c32) = hv;
        float ps = acc[i].x * as4.x + acc[i].y * as4.y + acc[i].z * as4.z + acc[i].w * as4.w;
        float pd = acc[i].x * ad4.x + acc[i].y * ad4.y + acc[i].z * ad4.z + acc[i].w * ad4.w;
#pragma unroll
        for (int m = 8; m >= 1; m >>= 1) {
            ps += __shfl_xor(ps, m, 16);
            pd += __shfl_xor(pd, m, 16);
        }
        if ((c32 & 15) == 0) {
            int head = c32 >> 4;
            as_out[row * 2 + head] = ps;
            ad_out[row * 2 + head] = pd;
        }
    }
}

// Aggregation: one wave per node. Lane c owns channels (2c, 2c+1); head=c>>5.
// Single 4-byte half2 gather per edge per lane; fp32 weights/accumulators.
__global__ __launch_bounds__(256) void k_agg(
    const _Float16* __restrict__ Hh, const float* __restrict__ as,
    const float* __restrict__ ad, const float* __restrict__ bias,
    const int* __restrict__ csr, const int* __restrict__ off,
    const int* __restrict__ deg, float* __restrict__ out, int n) {
    int wave = threadIdx.x >> 6, lane = threadIdx.x & 63;
    int node = blockIdx.x * 4 + wave;
    if (node >= n) return;
    int o = off[node], d = deg[node];
    int head = lane >> 5;
    float adh = ad[node * 2 + head];
    const _Float16* Hl = Hh + 2 * lane;        // lane-fixed channel offset
    const float* ash = as + head;
    float acc0 = 0.f, acc1 = 0.f, den = 0.f;
    int j = 0;
    for (; j + 8 <= d; j += 8) {
        int s0 = csr[o + j],     s1 = csr[o + j + 1];
        int s2 = csr[o + j + 2], s3 = csr[o + j + 3];
        int s4 = csr[o + j + 4], s5 = csr[o + j + 5];
        int s6 = csr[o + j + 6], s7 = csr[o + j + 7];
        float a0 = ash[s0 * 2], a1 = ash[s1 * 2], a2 = ash[s2 * 2], a3 = ash[s3 * 2];
        float a4 = ash[s4 * 2], a5 = ash[s5 * 2], a6 = ash[s6 * 2], a7 = ash[s7 * 2];
        h2v g0 = *(const h2v*)(Hl + (size_t)s0 * 128);
        h2v g1 = *(const h2v*)(Hl + (size_t)s1 * 128);
        h2v g2 = *(const h2v*)(Hl + (size_t)s2 * 128);
        h2v g3 = *(const h2v*)(Hl + (size_t)s3 * 128);
        h2v g4 = *(const h2v*)(Hl + (size_t)s4 * 128);
        h2v g5 = *(const h2v*)(Hl + (size_t)s5 * 128);
        h2v g6 = *(const h2v*)(Hl + (size_t)s6 * 128);
        h2v g7 = *(const h2v*)(Hl + (size_t)s7 * 128);
        float e, w;
        e = a0 + adh; e = fmaxf(e, 0.2f * e); w = __expf(e);
        den += w; acc0 += w * (float)g0.x; acc1 += w * (float)g0.y;
        e = a1 + adh; e = fmaxf(e, 0.2f * e); w = __expf(e);
        den += w; acc0 += w * (float)g1.x; acc1 += w * (float)g1.y;
        e = a2 + adh; e = fmaxf(e, 0.2f * e); w = __expf(e);
        den += w; acc0 += w * (float)g2.x; acc1 += w * (float)g2.y;
        e = a3 + adh; e = fmaxf(e, 0.2f * e); w = __expf(e);
        den += w; acc0 += w * (float)g3.x; acc1 += w * (float)g3.y;
        e = a4 + adh; e = fmaxf(e, 0.2f * e); w = __expf(e);
        den += w; acc0 += w * (float)g4.x; acc1 += w * (float)g4.y;
        e = a5 + adh; e = fmaxf(e, 0.2f * e); w = __expf(e);
        den += w; acc0 += w * (float)g5.x; acc1 += w * (float)g5.y;
        e = a6 + adh; e = fmaxf(e, 0.2f * e); w = __expf(e);
        den += w; acc0 += w * (float)g6.x; acc1 += w * (float)g6.y;
        e = a7 + adh; e = fmaxf(e, 0.2f * e); w = __expf(e);
        den += w; acc0 += w * (float)g7.x; acc1 += w * (float)g7.y;
    }
    for (; j < d; ++j) {
        int s = csr[o + j];
        float a = ash[s * 2];
        h2v g = *(const h2v*)(Hl + (size_t)s * 128);
        float e = a + adh; e = fmaxf(e, 0.2f * e);
        float w = __expf(e);
        den += w; acc0 += w * (float)g.x; acc1 += w * (float)g.y;
    }
    f32x2 b2 = *(const f32x2*)(bias + 2 * lane);
    float inv = 1.f / den;
    float r0 = acc0 * inv + b2.x;
    float r1 = acc1 * inv + b2.y;
    r0 = r0 > 0.f ? r0 : __expf(r0) - 1.f;   // ELU
    r1 = r1 > 0.f ? r1 : __expf(r1) - 1.f;
    f32x2 r; r.x = r0; r.y = r1;
    __builtin_nontemporal_store(r, (f32x2*)(out + (size_t)node * 128 + 2 * lane));
}

extern "C" void kernel_launch(void* const* d_in, const int* in_sizes, int n_in,
                              void* d_out, int out_size, void* d_ws, size_t ws_size,
                              hipStream_t stream) {
    const float* x   = (const float*)d_in[0];
    const int*   ei  = (const int*)d_in[1];
    const float* W1  = (const float*)d_in[2];
    const float* as1 = (const float*)d_in[3];
    const float* ad1 = (const float*)d_in[4];
    const float* b1  = (const float*)d_in[5];
    const float* W2  = (const float*)d_in[6];
    const float* as2 = (const float*)d_in[7];
    const float* ad2 = (const float*)d_in[8];
    const float* b2  = (const float*)d_in[9];

    const int N = in_sizes[0] / 128;
    const int E = in_sizes[1] / 2;

    // workspace carve-up
    _Float16* Hh    = (_Float16*)d_ws;                      // N*128 fp16
    float*  y1      = (float*)(Hh + (size_t)N * 128);       // N*128 fp32
    float*  alpha_s = y1 + (size_t)N * 128;                 // 2N
    float*  alpha_d = alpha_s + 2 * (size_t)N;              // 2N
    int*    deg     = (int*)(alpha_d + 2 * (size_t)N);
    int*    off     = deg + N;
    int*    bsum    = off + N;                              // 128
    int*    csr     = bsum + 128;                           // E+N
    // pos/pos_self alias y1: only live between k_hist and k_scatter,
    // both complete before layer-1 k_agg writes y1.
    int*    pos      = (int*)y1;                            // E
    int*    pos_self = pos + E;                             // N

    hipMemsetAsync(deg, 0, (size_t)N * 4, stream);

    int nb = (N + 1023) / 1024;
    k_hist<<<((E >> 2) + N + 255) / 256, 256, 0, stream>>>(ei, deg, pos, pos_self, E, N);
    k_scan_block<<<nb, 1024, 0, stream>>>(deg, off, bsum, N);
    k_scan_bsum<<<1, 128, 0, stream>>>(bsum, nb);
    k_scan_add<<<nb, 1024, 0, stream>>>(off, bsum, N);
    k_scatter<<<((E >> 2) + N + 255) / 256, 256, 0, stream>>>(ei, off, pos, pos_self, csr, E, N);

    // layer 1
    k_gemm_alpha<<<(N + 63) / 64, 256, 0, stream>>>(x, W1, as1, ad1, Hh, alpha_s, alpha_d, N);
    k_agg<<<(N + 3) / 4, 256, 0, stream>>>(Hh, alpha_s, alpha_d, b1, csr, off, deg, y1, N);

    // layer 2
    k_gemm_alpha<<<(N + 63) / 64, 256, 0, stream>>>(y1, W2, as2, ad2, Hh, alpha_s, alpha_d, N);
    k_agg<<<(N + 3) / 4, 256, 0, stream>>>(Hh, alpha_s, alpha_d, b2, csr, off, deg, (float*)d_out, N);
}

// Round 8
// 430.132 us; speedup vs baseline: 1.5002x; 1.1248x over previous
//
#include <hip/hip_runtime.h>

// ---------------------------------------------------------------------------
// GAT encoder, 2 layers, N=100K nodes, E=1.6M edges (+N self loops), F=128,
// heads=2 x 64ch.
//   1. dst-CSR built once: vectorized hist (atomicAdd returns slot) -> scan ->
//      atomic-free vectorized scatter. pos[] aliases the y1 buffer.
//   2. Per layer: GEMM h = x@W via MFMA 16x16x32_f16 (fp32 X read coalesced
//      into A-frags, W transposed+swizzled in LDS for b128 B-frags, fp32
//      accum), H stored fp16, alpha_src/alpha_dst fused fp32 epilogue; then
//      per-node wave aggregation: lane c owns channels (2c,2c+1) -> single
//      4-byte gather per edge, 8-deep pipelined, NT stores. y1 fp32.
//   Softmax max-subtraction skipped (logits bounded, exp safe in fp32).
// ---------------------------------------------------------------------------

typedef float    f32x2 __attribute__((ext_vector_type(2)));
typedef float    f32x4 __attribute__((ext_vector_type(4)));
typedef _Float16 h2v   __attribute__((ext_vector_type(2)));
typedef _Float16 h4v   __attribute__((ext_vector_type(4)));
typedef _Float16 f16x8 __attribute__((ext_vector_type(8)));

__global__ __launch_bounds__(256) void k_hist(const int* __restrict__ ei,
                                              int* __restrict__ deg,
                                              int* __restrict__ pos,
                                              int* __restrict__ pos_self,
                                              int E, int n) {
    int i = blockIdx.x * blockDim.x + threadIdx.x;
    int E4 = E >> 2;
    if (i < E4) {
        int4 d4 = ((const int4*)(ei + E))[i];
        int4 p;
        p.x = atomicAdd(&deg[d4.x], 1);
        p.y = atomicAdd(&deg[d4.y], 1);
        p.z = atomicAdd(&deg[d4.z], 1);
        p.w = atomicAdd(&deg[d4.w], 1);
        ((int4*)pos)[i] = p;
    } else if (i < E4 + n) {
        int nn = i - E4;
        pos_self[nn] = atomicAdd(&deg[nn], 1);
    }
    int tail = E & 3;
    if (i < tail) {
        int e = (E4 << 2) + i;
        pos[e] = atomicAdd(&deg[ei[E + e]], 1);
    }
}

__global__ __launch_bounds__(1024) void k_scan_block(const int* __restrict__ deg,
                                                     int* __restrict__ off,
                                                     int* __restrict__ bsum, int n) {
    __shared__ int tmp[1024];
    int t = threadIdx.x;
    int i = blockIdx.x * 1024 + t;
    int v = (i < n) ? deg[i] : 0;
    tmp[t] = v;
    __syncthreads();
    for (int d = 1; d < 1024; d <<= 1) {
        int a = (t >= d) ? tmp[t - d] : 0;
        __syncthreads();
        tmp[t] += a;
        __syncthreads();
    }
    if (i < n) off[i] = tmp[t] - v;             // exclusive
    if (t == 1023) bsum[blockIdx.x] = tmp[t];
}

__global__ __launch_bounds__(128) void k_scan_bsum(int* __restrict__ bsum, int nb) {
    __shared__ int tmp[128];
    int t = threadIdx.x;
    int v = (t < nb) ? bsum[t] : 0;
    tmp[t] = v;
    __syncthreads();
    for (int d = 1; d < 128; d <<= 1) {
        int a = (t >= d) ? tmp[t - d] : 0;
        __syncthreads();
        tmp[t] += a;
        __syncthreads();
    }
    if (t < nb) bsum[t] = tmp[t] - v;           // exclusive over block sums
}

__global__ __launch_bounds__(1024) void k_scan_add(int* __restrict__ off,
                                                   const int* __restrict__ bsum, int n) {
    int i = blockIdx.x * 1024 + threadIdx.x;
    if (i < n) off[i] += bsum[blockIdx.x];
}

// atomic-free scatter using hist-provided slots, 4 edges/thread
__global__ __launch_bounds__(256) void k_scatter(const int* __restrict__ ei,
                                                 const int* __restrict__ off,
                                                 const int* __restrict__ pos,
                                                 const int* __restrict__ pos_self,
                                                 int* __restrict__ csr, int E, int n) {
    int i = blockIdx.x * blockDim.x + threadIdx.x;
    int E4 = E >> 2;
    if (i < E4) {
        int4 s4 = ((const int4*)ei)[i];
        int4 d4 = ((const int4*)(ei + E))[i];
        int4 p4 = ((const int4*)pos)[i];
        csr[off[d4.x] + p4.x] = s4.x;
        csr[off[d4.y] + p4.y] = s4.y;
        csr[off[d4.z] + p4.z] = s4.z;
        csr[off[d4.w] + p4.w] = s4.w;
    } else if (i < E4 + n) {
        int nn = i - E4;
        csr[off[nn] + pos_self[nn]] = nn;
    }
    int tail = E & 3;
    if (i < tail) {
        int e = (E4 << 2) + i;
        int d = ei[E + e];
        csr[off[d] + pos[e]] = ei[e];
    }
}

// MFMA GEMM: H[row,col] = sum_k X[row,k]*W[k,col], fp16 in / fp32 acc.
// Block = 256 thr = 4 waves; wave w owns rows rowBase + w*16 .. +15.
// A-frag (per kstep kk): lane l holds X[row=base+(l&15)][kk*32+(l>>4)*8+j],
//   j=0..7 -> read straight from global (two float4), convert to f16x8.
// B-frag: W transposed in LDS ws_t[col][k] fp16, byte = col*256 + k*2,
//   XOR-swizzled ^((col&7)<<4) -> frag is one ds_read_b128, 2-way banked.
// C/D: col = lane&15, row = (lane>>4)*4 + reg (m89-verified mapping).
__global__ __launch_bounds__(256) void k_gemm_alpha(
    const float* __restrict__ X, const float* __restrict__ W,
    const float* __restrict__ a_src, const float* __restrict__ a_dst,
    _Float16* __restrict__ Hh, float* __restrict__ as_out, float* __restrict__ ad_out,
    int n) {
    __shared__ __attribute__((aligned(16))) char wsm[128 * 128 * 2];  // 32 KB
    int t = threadIdx.x;
    const float4* W4 = (const float4*)W;

    // stage W transposed + swizzled: element (k, col) -> byte col*256 + k*2
#pragma unroll
    for (int it = 0; it < 8; ++it) {
        int idx = t + it * 256;                  // 0..2047
        int kp = idx >> 5;                       // k-pair 0..63
        int seg = idx & 31;                      // 4 cols
        float4 wa = W4[(size_t)(2 * kp) * 32 + seg];
        float4 wb = W4[(size_t)(2 * kp + 1) * 32 + seg];
#pragma unroll
        for (int j = 0; j < 4; ++j) {
            int col = seg * 4 + j;
            h2v pr;
            pr.x = (_Float16)(&wa.x)[j];
            pr.y = (_Float16)(&wb.x)[j];
            int byte = (col << 8) + (kp << 2);
            byte ^= (col & 7) << 4;
            *(h2v*)(wsm + byte) = pr;
        }
    }

    int wid = t >> 6, l = t & 63;
    int c16 = l & 15, hi = l >> 4;
    int rowBase = blockIdx.x * 64 + wid * 16;
    int myRow = rowBase + c16;
    int rowc = myRow < n ? myRow : (n - 1);      // clamped for loads

    // A-frags from global (coalesced: wave covers 16 rows x 128B per kstep)
    f16x8 af[4];
    {
        const float4* Xr = (const float4*)(X + (size_t)rowc * 128);
#pragma unroll
        for (int kk = 0; kk < 4; ++kk) {
            float4 va = Xr[kk * 8 + hi * 2];
            float4 vb = Xr[kk * 8 + hi * 2 + 1];
            f16x8 a;
            a[0] = (_Float16)va.x; a[1] = (_Float16)va.y;
            a[2] = (_Float16)va.z; a[3] = (_Float16)va.w;
            a[4] = (_Float16)vb.x; a[5] = (_Float16)vb.y;
            a[6] = (_Float16)vb.z; a[7] = (_Float16)vb.w;
            af[kk] = a;
        }
    }

    // alpha coefficients for this lane's columns (col = ct*16 + c16)
    float asv[8], adv[8];
#pragma unroll
    for (int ct = 0; ct < 8; ++ct) {
        asv[ct] = a_src[ct * 16 + c16];
        adv[ct] = a_dst[ct * 16 + c16];
    }

    __syncthreads();

    float psum_s[2][4] = {{0.f,0.f,0.f,0.f},{0.f,0.f,0.f,0.f}};
    float psum_d[2][4] = {{0.f,0.f,0.f,0.f},{0.f,0.f,0.f,0.f}};

#pragma unroll
    for (int ct = 0; ct < 8; ++ct) {
        int col = ct * 16 + c16;
        int cswz = (col & 7) << 4;
        f32x4 acc = {0.f, 0.f, 0.f, 0.f};
#pragma unroll
        for (int kk = 0; kk < 4; ++kk) {
            int byte = ((col << 8) + (kk << 6) + (hi << 4)) ^ cswz;
            f16x8 bf = *(const f16x8*)(wsm + byte);
            acc = __builtin_amdgcn_mfma_f32_16x16x32_f16(af[kk], bf, acc, 0, 0, 0);
        }
        int head = ct >> 2;
#pragma unroll
        for (int reg = 0; reg < 4; ++reg) {
            int row = rowBase + hi * 4 + reg;
            float v = acc[reg];
            if (row < n)
                Hh[(size_t)row * 128 + col] = (_Float16)v;
            psum_s[head][reg] += v * asv[ct];
            psum_d[head][reg] += v * adv[ct];
        }
    }

    // reduce alpha partials over the 16 lanes sharing each row (width-16)
#pragma unroll
    for (int head = 0; head < 2; ++head) {
#pragma unroll
        for (int reg = 0; reg < 4; ++reg) {
            float ps = psum_s[head][reg];
            float pd = psum_d[head][reg];
#pragma unroll
            for (int m = 8; m >= 1; m >>= 1) {
                ps += __shfl_xor(ps, m, 16);
                pd += __shfl_xor(pd, m, 16);
            }
            if (c16 == 0) {
                int row = rowBase + hi * 4 + reg;
                if (row < n) {
                    as_out[row * 2 + head] = ps;
                    ad_out[row * 2 + head] = pd;
                }
            }
        }
    }
}

// Aggregation: one wave per node. Lane c owns channels (2c, 2c+1); head=c>>5.
// Single 4-byte half2 gather per edge per lane; fp32 weights/accumulators.
__global__ __launch_bounds__(256) void k_agg(
    const _Float16* __restrict__ Hh, const float* __restrict__ as,
    const float* __restrict__ ad, const float* __restrict__ bias,
    const int* __restrict__ csr, const int* __restrict__ off,
    const int* __restrict__ deg, float* __restrict__ out, int n) {
    int wave = threadIdx.x >> 6, lane = threadIdx.x & 63;
    int node = blockIdx.x * 4 + wave;
    if (node >= n) return;
    int o = off[node], d = deg[node];
    int head = lane >> 5;
    float adh = ad[node * 2 + head];
    const _Float16* Hl = Hh + 2 * lane;        // lane-fixed channel offset
    const float* ash = as + head;
    float acc0 = 0.f, acc1 = 0.f, den = 0.f;
    int j = 0;
    for (; j + 8 <= d; j += 8) {
        int s0 = csr[o + j],     s1 = csr[o + j + 1];
        int s2 = csr[o + j + 2], s3 = csr[o + j + 3];
        int s4 = csr[o + j + 4], s5 = csr[o + j + 5];
        int s6 = csr[o + j + 6], s7 = csr[o + j + 7];
        float a0 = ash[s0 * 2], a1 = ash[s1 * 2], a2 = ash[s2 * 2], a3 = ash[s3 * 2];
        float a4 = ash[s4 * 2], a5 = ash[s5 * 2], a6 = ash[s6 * 2], a7 = ash[s7 * 2];
        h2v g0 = *(const h2v*)(Hl + (size_t)s0 * 128);
        h2v g1 = *(const h2v*)(Hl + (size_t)s1 * 128);
        h2v g2 = *(const h2v*)(Hl + (size_t)s2 * 128);
        h2v g3 = *(const h2v*)(Hl + (size_t)s3 * 128);
        h2v g4 = *(const h2v*)(Hl + (size_t)s4 * 128);
        h2v g5 = *(const h2v*)(Hl + (size_t)s5 * 128);
        h2v g6 = *(const h2v*)(Hl + (size_t)s6 * 128);
        h2v g7 = *(const h2v*)(Hl + (size_t)s7 * 128);
        float e, w;
        e = a0 + adh; e = fmaxf(e, 0.2f * e); w = __expf(e);
        den += w; acc0 += w * (float)g0.x; acc1 += w * (float)g0.y;
        e = a1 + adh; e = fmaxf(e, 0.2f * e); w = __expf(e);
        den += w; acc0 += w * (float)g1.x; acc1 += w * (float)g1.y;
        e = a2 + adh; e = fmaxf(e, 0.2f * e); w = __expf(e);
        den += w; acc0 += w * (float)g2.x; acc1 += w * (float)g2.y;
        e = a3 + adh; e = fmaxf(e, 0.2f * e); w = __expf(e);
        den += w; acc0 += w * (float)g3.x; acc1 += w * (float)g3.y;
        e = a4 + adh; e = fmaxf(e, 0.2f * e); w = __expf(e);
        den += w; acc0 += w * (float)g4.x; acc1 += w * (float)g4.y;
        e = a5 + adh; e = fmaxf(e, 0.2f * e); w = __expf(e);
        den += w; acc0 += w * (float)g5.x; acc1 += w * (float)g5.y;
        e = a6 + adh; e = fmaxf(e, 0.2f * e); w = __expf(e);
        den += w; acc0 += w * (float)g6.x; acc1 += w * (float)g6.y;
        e = a7 + adh; e = fmaxf(e, 0.2f * e); w = __expf(e);
        den += w; acc0 += w * (float)g7.x; acc1 += w * (float)g7.y;
    }
    for (; j < d; ++j) {
        int s = csr[o + j];
        float a = ash[s * 2];
        h2v g = *(const h2v*)(Hl + (size_t)s * 128);
        float e = a + adh; e = fmaxf(e, 0.2f * e);
        float w = __expf(e);
        den += w; acc0 += w * (float)g.x; acc1 += w * (float)g.y;
    }
    f32x2 b2 = *(const f32x2*)(bias + 2 * lane);
    float inv = 1.f / den;
    float r0 = acc0 * inv + b2.x;
    float r1 = acc1 * inv + b2.y;
    r0 = r0 > 0.f ? r0 : __expf(r0) - 1.f;   // ELU
    r1 = r1 > 0.f ? r1 : __expf(r1) - 1.f;
    f32x2 r; r.x = r0; r.y = r1;
    __builtin_nontemporal_store(r, (f32x2*)(out + (size_t)node * 128 + 2 * lane));
}

extern "C" void kernel_launch(void* const* d_in, const int* in_sizes, int n_in,
                              void* d_out, int out_size, void* d_ws, size_t ws_size,
                              hipStream_t stream) {
    const float* x   = (const float*)d_in[0];
    const int*   ei  = (const int*)d_in[1];
    const float* W1  = (const float*)d_in[2];
    const float* as1 = (const float*)d_in[3];
    const float* ad1 = (const float*)d_in[4];
    const float* b1  = (const float*)d_in[5];
    const float* W2  = (const float*)d_in[6];
    const float* as2 = (const float*)d_in[7];
    const float* ad2 = (const float*)d_in[8];
    const float* b2  = (const float*)d_in[9];

    const int N = in_sizes[0] / 128;
    const int E = in_sizes[1] / 2;

    // workspace carve-up
    _Float16* Hh    = (_Float16*)d_ws;                      // N*128 fp16
    float*  y1      = (float*)(Hh + (size_t)N * 128);       // N*128 fp32
    float*  alpha_s = y1 + (size_t)N * 128;                 // 2N
    float*  alpha_d = alpha_s + 2 * (size_t)N;              // 2N
    int*    deg     = (int*)(alpha_d + 2 * (size_t)N);
    int*    off     = deg + N;
    int*    bsum    = off + N;                              // 128
    int*    csr     = bsum + 128;                           // E+N
    // pos/pos_self alias y1: only live between k_hist and k_scatter,
    // both complete before layer-1 k_agg writes y1.
    int*    pos      = (int*)y1;                            // E
    int*    pos_self = pos + E;                             // N

    hipMemsetAsync(deg, 0, (size_t)N * 4, stream);

    int nb = (N + 1023) / 1024;
    k_hist<<<((E >> 2) + N + 255) / 256, 256, 0, stream>>>(ei, deg, pos, pos_self, E, N);
    k_scan_block<<<nb, 1024, 0, stream>>>(deg, off, bsum, N);
    k_scan_bsum<<<1, 128, 0, stream>>>(bsum, nb);
    k_scan_add<<<nb, 1024, 0, stream>>>(off, bsum, N);
    k_scatter<<<((E >> 2) + N + 255) / 256, 256, 0, stream>>>(ei, off, pos, pos_self, csr, E, N);

    // layer 1
    k_gemm_alpha<<<(N + 63) / 64, 256, 0, stream>>>(x, W1, as1, ad1, Hh, alpha_s, alpha_d, N);
    k_agg<<<(N + 3) / 4, 256, 0, stream>>>(Hh, alpha_s, alpha_d, b1, csr, off, deg, y1, N);

    // layer 2
    k_gemm_alpha<<<(N + 63) / 64, 256, 0, stream>>>(y1, W2, as2, ad2, Hh, alpha_s, alpha_d, N);
    k_agg<<<(N + 3) / 4, 256, 0, stream>>>(Hh, alpha_s, alpha_d, b2, csr, off, deg, (float*)d_out, N);
}

// Round 9
// 419.061 us; speedup vs baseline: 1.5398x; 1.0264x over previous
//
#include <hip/hip_runtime.h>

// ---------------------------------------------------------------------------
// GAT encoder, 2 layers, N=100K nodes, E=1.6M edges (+N self loops), F=128,
// heads=2 x 64ch.
//   1. dst-CSR built once: vectorized hist (atomicAdd returns slot) -> scan ->
//      atomic-free vectorized scatter. pos[] aliases the y1 buffer.
//   2. Per layer: GEMM h = x@W via MFMA 16x16x32_f16 (fp32 X read coalesced
//      into A-frags, W transposed+swizzled in LDS for b128 B-frags, fp32
//      accum), H stored fp16, alpha fused fp32 epilogue; then per-node wave
//      aggregation v2: per 64-edge chunk, phase A computes all edge weights
//      lane-parallel (2 exp per EDGE, not per lane) into LDS; phase B
//      replays via broadcast ds_read_b128 + single 4-byte H-gather/edge.
//   Softmax max-subtraction skipped (logits bounded, exp safe in fp32).
// ---------------------------------------------------------------------------

typedef float    f32x2 __attribute__((ext_vector_type(2)));
typedef float    f32x4 __attribute__((ext_vector_type(4)));
typedef _Float16 h2v   __attribute__((ext_vector_type(2)));
typedef _Float16 h4v   __attribute__((ext_vector_type(4)));
typedef _Float16 f16x8 __attribute__((ext_vector_type(8)));

__global__ __launch_bounds__(256) void k_hist(const int* __restrict__ ei,
                                              int* __restrict__ deg,
                                              int* __restrict__ pos,
                                              int* __restrict__ pos_self,
                                              int E, int n) {
    int i = blockIdx.x * blockDim.x + threadIdx.x;
    int E4 = E >> 2;
    if (i < E4) {
        int4 d4 = ((const int4*)(ei + E))[i];
        int4 p;
        p.x = atomicAdd(&deg[d4.x], 1);
        p.y = atomicAdd(&deg[d4.y], 1);
        p.z = atomicAdd(&deg[d4.z], 1);
        p.w = atomicAdd(&deg[d4.w], 1);
        ((int4*)pos)[i] = p;
    } else if (i < E4 + n) {
        int nn = i - E4;
        pos_self[nn] = atomicAdd(&deg[nn], 1);
    }
    int tail = E & 3;
    if (i < tail) {
        int e = (E4 << 2) + i;
        pos[e] = atomicAdd(&deg[ei[E + e]], 1);
    }
}

__global__ __launch_bounds__(1024) void k_scan_block(const int* __restrict__ deg,
                                                     int* __restrict__ off,
                                                     int* __restrict__ bsum, int n) {
    __shared__ int tmp[1024];
    int t = threadIdx.x;
    int i = blockIdx.x * 1024 + t;
    int v = (i < n) ? deg[i] : 0;
    tmp[t] = v;
    __syncthreads();
    for (int d = 1; d < 1024; d <<= 1) {
        int a = (t >= d) ? tmp[t - d] : 0;
        __syncthreads();
        tmp[t] += a;
        __syncthreads();
    }
    if (i < n) off[i] = tmp[t] - v;             // exclusive
    if (t == 1023) bsum[blockIdx.x] = tmp[t];
}

__global__ __launch_bounds__(128) void k_scan_bsum(int* __restrict__ bsum, int nb) {
    __shared__ int tmp[128];
    int t = threadIdx.x;
    int v = (t < nb) ? bsum[t] : 0;
    tmp[t] = v;
    __syncthreads();
    for (int d = 1; d < 128; d <<= 1) {
        int a = (t >= d) ? tmp[t - d] : 0;
        __syncthreads();
        tmp[t] += a;
        __syncthreads();
    }
    if (t < nb) bsum[t] = tmp[t] - v;           // exclusive over block sums
}

__global__ __launch_bounds__(1024) void k_scan_add(int* __restrict__ off,
                                                   const int* __restrict__ bsum, int n) {
    int i = blockIdx.x * 1024 + threadIdx.x;
    if (i < n) off[i] += bsum[blockIdx.x];
}

// atomic-free scatter using hist-provided slots, 4 edges/thread
__global__ __launch_bounds__(256) void k_scatter(const int* __restrict__ ei,
                                                 const int* __restrict__ off,
                                                 const int* __restrict__ pos,
                                                 const int* __restrict__ pos_self,
                                                 int* __restrict__ csr, int E, int n) {
    int i = blockIdx.x * blockDim.x + threadIdx.x;
    int E4 = E >> 2;
    if (i < E4) {
        int4 s4 = ((const int4*)ei)[i];
        int4 d4 = ((const int4*)(ei + E))[i];
        int4 p4 = ((const int4*)pos)[i];
        csr[off[d4.x] + p4.x] = s4.x;
        csr[off[d4.y] + p4.y] = s4.y;
        csr[off[d4.z] + p4.z] = s4.z;
        csr[off[d4.w] + p4.w] = s4.w;
    } else if (i < E4 + n) {
        int nn = i - E4;
        csr[off[nn] + pos_self[nn]] = nn;
    }
    int tail = E & 3;
    if (i < tail) {
        int e = (E4 << 2) + i;
        int d = ei[E + e];
        csr[off[d] + pos[e]] = ei[e];
    }
}

// MFMA GEMM: H[row,col] = sum_k X[row,k]*W[k,col], fp16 in / fp32 acc.
// (unchanged from round 8 — validated absmax 9.8e-4)
__global__ __launch_bounds__(256) void k_gemm_alpha(
    const float* __restrict__ X, const float* __restrict__ W,
    const float* __restrict__ a_src, const float* __restrict__ a_dst,
    _Float16* __restrict__ Hh, float* __restrict__ as_out, float* __restrict__ ad_out,
    int n) {
    __shared__ __attribute__((aligned(16))) char wsm[128 * 128 * 2];  // 32 KB
    int t = threadIdx.x;
    const float4* W4 = (const float4*)W;

    // stage W transposed + swizzled: element (k, col) -> byte col*256 + k*2
#pragma unroll
    for (int it = 0; it < 8; ++it) {
        int idx = t + it * 256;                  // 0..2047
        int kp = idx >> 5;                       // k-pair 0..63
        int seg = idx & 31;                      // 4 cols
        float4 wa = W4[(size_t)(2 * kp) * 32 + seg];
        float4 wb = W4[(size_t)(2 * kp + 1) * 32 + seg];
#pragma unroll
        for (int j = 0; j < 4; ++j) {
            int col = seg * 4 + j;
            h2v pr;
            pr.x = (_Float16)(&wa.x)[j];
            pr.y = (_Float16)(&wb.x)[j];
            int byte = (col << 8) + (kp << 2);
            byte ^= (col & 7) << 4;
            *(h2v*)(wsm + byte) = pr;
        }
    }

    int wid = t >> 6, l = t & 63;
    int c16 = l & 15, hi = l >> 4;
    int rowBase = blockIdx.x * 64 + wid * 16;
    int myRow = rowBase + c16;
    int rowc = myRow < n ? myRow : (n - 1);      // clamped for loads

    // A-frags from global (coalesced: wave covers 16 rows x 128B per kstep)
    f16x8 af[4];
    {
        const float4* Xr = (const float4*)(X + (size_t)rowc * 128);
#pragma unroll
        for (int kk = 0; kk < 4; ++kk) {
            float4 va = Xr[kk * 8 + hi * 2];
            float4 vb = Xr[kk * 8 + hi * 2 + 1];
            f16x8 a;
            a[0] = (_Float16)va.x; a[1] = (_Float16)va.y;
            a[2] = (_Float16)va.z; a[3] = (_Float16)va.w;
            a[4] = (_Float16)vb.x; a[5] = (_Float16)vb.y;
            a[6] = (_Float16)vb.z; a[7] = (_Float16)vb.w;
            af[kk] = a;
        }
    }

    // alpha coefficients for this lane's columns (col = ct*16 + c16)
    float asv[8], adv[8];
#pragma unroll
    for (int ct = 0; ct < 8; ++ct) {
        asv[ct] = a_src[ct * 16 + c16];
        adv[ct] = a_dst[ct * 16 + c16];
    }

    __syncthreads();

    float psum_s[2][4] = {{0.f,0.f,0.f,0.f},{0.f,0.f,0.f,0.f}};
    float psum_d[2][4] = {{0.f,0.f,0.f,0.f},{0.f,0.f,0.f,0.f}};

#pragma unroll
    for (int ct = 0; ct < 8; ++ct) {
        int col = ct * 16 + c16;
        int cswz = (col & 7) << 4;
        f32x4 acc = {0.f, 0.f, 0.f, 0.f};
#pragma unroll
        for (int kk = 0; kk < 4; ++kk) {
            int byte = ((col << 8) + (kk << 6) + (hi << 4)) ^ cswz;
            f16x8 bf = *(const f16x8*)(wsm + byte);
            acc = __builtin_amdgcn_mfma_f32_16x16x32_f16(af[kk], bf, acc, 0, 0, 0);
        }
        int head = ct >> 2;
#pragma unroll
        for (int reg = 0; reg < 4; ++reg) {
            int row = rowBase + hi * 4 + reg;
            float v = acc[reg];
            if (row < n)
                Hh[(size_t)row * 128 + col] = (_Float16)v;
            psum_s[head][reg] += v * asv[ct];
            psum_d[head][reg] += v * adv[ct];
        }
    }

    // reduce alpha partials over the 16 lanes sharing each row (width-16)
#pragma unroll
    for (int head = 0; head < 2; ++head) {
#pragma unroll
        for (int reg = 0; reg < 4; ++reg) {
            float ps = psum_s[head][reg];
            float pd = psum_d[head][reg];
#pragma unroll
            for (int m = 8; m >= 1; m >>= 1) {
                ps += __shfl_xor(ps, m, 16);
                pd += __shfl_xor(pd, m, 16);
            }
            if (c16 == 0) {
                int row = rowBase + hi * 4 + reg;
                if (row < n) {
                    as_out[row * 2 + head] = ps;
                    ad_out[row * 2 + head] = pd;
                }
            }
        }
    }
}

// Aggregation v2: one wave per node. Lane c owns channels (2c,2c+1); head=c>>5.
// Per 64-edge chunk: phase A computes all edge weights lane-parallel (one
// exp pair per EDGE) into LDS {s,w0,w1}; phase B replays via broadcast
// ds_read_b128 + one 4-byte H gather per edge. Same-wave LDS, no barrier.
__global__ __launch_bounds__(256) void k_agg(
    const _Float16* __restrict__ Hh, const float* __restrict__ as,
    const float* __restrict__ ad, const float* __restrict__ bias,
    const int* __restrict__ csr, const int* __restrict__ off,
    const int* __restrict__ deg, float* __restrict__ out, int n) {
    __shared__ int4 swbuf[4][64];               // 4 KB: per-wave edge packets
    int wave = threadIdx.x >> 6, lane = threadIdx.x & 63;
    int node = blockIdx.x * 4 + wave;
    if (node >= n) return;
    int o = off[node], d = deg[node];
    int head = lane >> 5;
    f32x2 adp = *(const f32x2*)(ad + (size_t)node * 2);
    const _Float16* Hl = Hh + 2 * lane;         // lane-fixed channel offset
    float acc0 = 0.f, acc1 = 0.f, den0 = 0.f, den1 = 0.f;

    for (int base = 0; base < d; base += 64) {
        int rem = d - base;
        // ---- phase A: lane j handles edge base+j ----
        int jj = lane < rem ? lane : (rem - 1);
        int s = csr[o + base + jj];
        f32x2 a2 = *(const f32x2*)(as + (size_t)s * 2);
        float e0 = a2.x + adp.x; e0 = fmaxf(e0, 0.2f * e0);
        float e1 = a2.y + adp.y; e1 = fmaxf(e1, 0.2f * e1);
        float w0 = __expf(e0), w1 = __expf(e1);
        if (lane >= rem) { w0 = 0.f; w1 = 0.f; }
        den0 += w0; den1 += w1;
        int4 pk;
        pk.x = s; pk.y = __float_as_int(w0); pk.z = __float_as_int(w1); pk.w = 0;
        swbuf[wave][lane] = pk;                 // in-wave producer/consumer

        // ---- phase B: replay m edges ----
        int m = rem < 64 ? rem : 64;
        int j = 0;
        for (; j + 4 <= m; j += 4) {
            int4 p0 = swbuf[wave][j + 0];
            int4 p1 = swbuf[wave][j + 1];
            int4 p2 = swbuf[wave][j + 2];
            int4 p3 = swbuf[wave][j + 3];
            h2v g0 = *(const h2v*)(Hl + (size_t)p0.x * 128);
            h2v g1 = *(const h2v*)(Hl + (size_t)p1.x * 128);
            h2v g2 = *(const h2v*)(Hl + (size_t)p2.x * 128);
            h2v g3 = *(const h2v*)(Hl + (size_t)p3.x * 128);
            float w0_ = __int_as_float(head ? p0.z : p0.y);
            float w1_ = __int_as_float(head ? p1.z : p1.y);
            float w2_ = __int_as_float(head ? p2.z : p2.y);
            float w3_ = __int_as_float(head ? p3.z : p3.y);
            acc0 += w0_ * (float)g0.x; acc1 += w0_ * (float)g0.y;
            acc0 += w1_ * (float)g1.x; acc1 += w1_ * (float)g1.y;
            acc0 += w2_ * (float)g2.x; acc1 += w2_ * (float)g2.y;
            acc0 += w3_ * (float)g3.x; acc1 += w3_ * (float)g3.y;
        }
        for (; j < m; ++j) {
            int4 p = swbuf[wave][j];
            h2v g = *(const h2v*)(Hl + (size_t)p.x * 128);
            float w = __int_as_float(head ? p.z : p.y);
            acc0 += w * (float)g.x; acc1 += w * (float)g.y;
        }
    }

    // reduce denominators across the wave (each lane holds partial sums)
#pragma unroll
    for (int mk = 1; mk < 64; mk <<= 1) {
        den0 += __shfl_xor(den0, mk, 64);
        den1 += __shfl_xor(den1, mk, 64);
    }
    float den = head ? den1 : den0;

    f32x2 b2 = *(const f32x2*)(bias + 2 * lane);
    float inv = 1.f / den;
    float r0 = acc0 * inv + b2.x;
    float r1 = acc1 * inv + b2.y;
    r0 = r0 > 0.f ? r0 : __expf(r0) - 1.f;   // ELU
    r1 = r1 > 0.f ? r1 : __expf(r1) - 1.f;
    f32x2 r; r.x = r0; r.y = r1;
    __builtin_nontemporal_store(r, (f32x2*)(out + (size_t)node * 128 + 2 * lane));
}

extern "C" void kernel_launch(void* const* d_in, const int* in_sizes, int n_in,
                              void* d_out, int out_size, void* d_ws, size_t ws_size,
                              hipStream_t stream) {
    const float* x   = (const float*)d_in[0];
    const int*   ei  = (const int*)d_in[1];
    const float* W1  = (const float*)d_in[2];
    const float* as1 = (const float*)d_in[3];
    const float* ad1 = (const float*)d_in[4];
    const float* b1  = (const float*)d_in[5];
    const float* W2  = (const float*)d_in[6];
    const float* as2 = (const float*)d_in[7];
    const float* ad2 = (const float*)d_in[8];
    const float* b2  = (const float*)d_in[9];

    const int N = in_sizes[0] / 128;
    const int E = in_sizes[1] / 2;

    // workspace carve-up
    _Float16* Hh    = (_Float16*)d_ws;                      // N*128 fp16
    float*  y1      = (float*)(Hh + (size_t)N * 128);       // N*128 fp32
    float*  alpha_s = y1 + (size_t)N * 128;                 // 2N
    float*  alpha_d = alpha_s + 2 * (size_t)N;              // 2N
    int*    deg     = (int*)(alpha_d + 2 * (size_t)N);
    int*    off     = deg + N;
    int*    bsum    = off + N;                              // 128
    int*    csr     = bsum + 128;                           // E+N
    // pos/pos_self alias y1: only live between k_hist and k_scatter,
    // both complete before layer-1 k_agg writes y1.
    int*    pos      = (int*)y1;                            // E
    int*    pos_self = pos + E;                             // N

    hipMemsetAsync(deg, 0, (size_t)N * 4, stream);

    int nb = (N + 1023) / 1024;
    k_hist<<<((E >> 2) + N + 255) / 256, 256, 0, stream>>>(ei, deg, pos, pos_self, E, N);
    k_scan_block<<<nb, 1024, 0, stream>>>(deg, off, bsum, N);
    k_scan_bsum<<<1, 128, 0, stream>>>(bsum, nb);
    k_scan_add<<<nb, 1024, 0, stream>>>(off, bsum, N);
    k_scatter<<<((E >> 2) + N + 255) / 256, 256, 0, stream>>>(ei, off, pos, pos_self, csr, E, N);

    // layer 1
    k_gemm_alpha<<<(N + 63) / 64, 256, 0, stream>>>(x, W1, as1, ad1, Hh, alpha_s, alpha_d, N);
    k_agg<<<(N + 3) / 4, 256, 0, stream>>>(Hh, alpha_s, alpha_d, b1, csr, off, deg, y1, N);

    // layer 2
    k_gemm_alpha<<<(N + 63) / 64, 256, 0, stream>>>(y1, W2, as2, ad2, Hh, alpha_s, alpha_d, N);
    k_agg<<<(N + 3) / 4, 256, 0, stream>>>(Hh, alpha_s, alpha_d, b2, csr, off, deg, (float*)d_out, N);
}

// Round 11
// 415.714 us; speedup vs baseline: 1.5522x; 1.0081x over previous
//
#include <hip/hip_runtime.h>

// ---------------------------------------------------------------------------
// GAT encoder, 2 layers, N=100K nodes, E=1.6M edges (+N self loops), F=128,
// heads=2 x 64ch.
//   0. k_wprep: one-time transpose of W1/W2 into global fp16 images in the
//      exact (pre-swizzled) LDS layout the GEMM B-frags read -> GEMM staging
//      is a linear conflict-free 16B copy.
//   1. dst-CSR built once: vectorized hist (atomicAdd returns slot) -> scan ->
//      atomic-free vectorized scatter. pos[] aliases the y1 buffer.
//   2. Per layer: GEMM h = x@W via MFMA 16x16x32_f16 (fp32 X read coalesced
//      into A-frags, pre-swizzled W image staged to LDS, fp32 accum), H
//      stored fp16, alpha fused fp32 epilogue; then per-node wave aggregation
//      v2: per 64-edge chunk, phase A computes all edge weights lane-parallel
//      into LDS; phase B replays via broadcast ds_read + 4-byte H-gather,
//      8-deep pipelined. NT output stores. y1 fp32.
//   Softmax max-subtraction skipped (logits bounded, exp safe in fp32).
// ---------------------------------------------------------------------------

typedef float    f32x2 __attribute__((ext_vector_type(2)));
typedef float    f32x4 __attribute__((ext_vector_type(4)));
typedef _Float16 h2v   __attribute__((ext_vector_type(2)));
typedef _Float16 f16x8 __attribute__((ext_vector_type(8)));

// Transpose W (fp32 [k][col]) into byte image: h2v (W[2kp][col],W[2kp+1][col])
// at byte (col<<8) + (kp<<2) ^ ((col&7)<<4). Handles both layers' W.
__global__ __launch_bounds__(256) void k_wprep(const float* __restrict__ W1,
                                               const float* __restrict__ W2,
                                               char* __restrict__ Wt1,
                                               char* __restrict__ Wt2) {
    int gid = blockIdx.x * 256 + threadIdx.x;   // 0..16383
    const float* W = (gid >> 13) ? W2 : W1;
    char* Wt = (gid >> 13) ? Wt2 : Wt1;
    int id = gid & 8191;                         // 0..8191
    int col = id >> 6, kp = id & 63;
    h2v pr;
    pr.x = (_Float16)W[(2 * kp) * 128 + col];
    pr.y = (_Float16)W[(2 * kp + 1) * 128 + col];
    int byte = ((col << 8) + (kp << 2)) ^ ((col & 7) << 4);
    *(h2v*)(Wt + byte) = pr;
}

__global__ __launch_bounds__(256) void k_hist(const int* __restrict__ ei,
                                              int* __restrict__ deg,
                                              int* __restrict__ pos,
                                              int* __restrict__ pos_self,
                                              int E, int n) {
    int i = blockIdx.x * blockDim.x + threadIdx.x;
    int E4 = E >> 2;
    if (i < E4) {
        int4 d4 = ((const int4*)(ei + E))[i];
        int4 p;
        p.x = atomicAdd(&deg[d4.x], 1);
        p.y = atomicAdd(&deg[d4.y], 1);
        p.z = atomicAdd(&deg[d4.z], 1);
        p.w = atomicAdd(&deg[d4.w], 1);
        ((int4*)pos)[i] = p;
    } else if (i < E4 + n) {
        int nn = i - E4;
        pos_self[nn] = atomicAdd(&deg[nn], 1);
    }
    int tail = E & 3;
    if (i < tail) {
        int e = (E4 << 2) + i;
        pos[e] = atomicAdd(&deg[ei[E + e]], 1);
    }
}

__global__ __launch_bounds__(1024) void k_scan_block(const int* __restrict__ deg,
                                                     int* __restrict__ off,
                                                     int* __restrict__ bsum, int n) {
    __shared__ int tmp[1024];
    int t = threadIdx.x;
    int i = blockIdx.x * 1024 + t;
    int v = (i < n) ? deg[i] : 0;
    tmp[t] = v;
    __syncthreads();
    for (int d = 1; d < 1024; d <<= 1) {
        int a = (t >= d) ? tmp[t - d] : 0;
        __syncthreads();
        tmp[t] += a;
        __syncthreads();
    }
    if (i < n) off[i] = tmp[t] - v;             // exclusive
    if (t == 1023) bsum[blockIdx.x] = tmp[t];
}

__global__ __launch_bounds__(128) void k_scan_bsum(int* __restrict__ bsum, int nb) {
    __shared__ int tmp[128];
    int t = threadIdx.x;
    int v = (t < nb) ? bsum[t] : 0;
    tmp[t] = v;
    __syncthreads();
    for (int d = 1; d < 128; d <<= 1) {
        int a = (t >= d) ? tmp[t - d] : 0;
        __syncthreads();
        tmp[t] += a;
        __syncthreads();
    }
    if (t < nb) bsum[t] = tmp[t] - v;           // exclusive over block sums
}

__global__ __launch_bounds__(1024) void k_scan_add(int* __restrict__ off,
                                                   const int* __restrict__ bsum, int n) {
    int i = blockIdx.x * 1024 + threadIdx.x;
    if (i < n) off[i] += bsum[blockIdx.x];
}

// atomic-free scatter using hist-provided slots, 4 edges/thread
__global__ __launch_bounds__(256) void k_scatter(const int* __restrict__ ei,
                                                 const int* __restrict__ off,
                                                 const int* __restrict__ pos,
                                                 const int* __restrict__ pos_self,
                                                 int* __restrict__ csr, int E, int n) {
    int i = blockIdx.x * blockDim.x + threadIdx.x;
    int E4 = E >> 2;
    if (i < E4) {
        int4 s4 = ((const int4*)ei)[i];
        int4 d4 = ((const int4*)(ei + E))[i];
        int4 p4 = ((const int4*)pos)[i];
        csr[off[d4.x] + p4.x] = s4.x;
        csr[off[d4.y] + p4.y] = s4.y;
        csr[off[d4.z] + p4.z] = s4.z;
        csr[off[d4.w] + p4.w] = s4.w;
    } else if (i < E4 + n) {
        int nn = i - E4;
        csr[off[nn] + pos_self[nn]] = nn;
    }
    int tail = E & 3;
    if (i < tail) {
        int e = (E4 << 2) + i;
        int d = ei[E + e];
        csr[off[d] + pos[e]] = ei[e];
    }
}

// MFMA GEMM: H[row,col] = sum_k X[row,k]*W[k,col], fp16 in / fp32 acc.
// B operand staged from pre-transposed+swizzled global image (linear copy).
__global__ __launch_bounds__(256) void k_gemm_alpha(
    const float* __restrict__ X, const char* __restrict__ Wt,
    const float* __restrict__ a_src, const float* __restrict__ a_dst,
    _Float16* __restrict__ Hh, float* __restrict__ as_out, float* __restrict__ ad_out,
    int n) {
    __shared__ __attribute__((aligned(16))) char wsm[128 * 128 * 2];  // 32 KB
    int t = threadIdx.x;

    // linear conflict-free staging of the pre-swizzled W image
    {
        const float4* src = (const float4*)Wt;
        float4* dst = (float4*)wsm;
#pragma unroll
        for (int it = 0; it < 8; ++it)
            dst[t + it * 256] = src[t + it * 256];
    }

    int wid = t >> 6, l = t & 63;
    int c16 = l & 15, hi = l >> 4;
    int rowBase = blockIdx.x * 64 + wid * 16;
    int myRow = rowBase + c16;
    int rowc = myRow < n ? myRow : (n - 1);      // clamped for loads

    // A-frags from global (coalesced: wave covers 16 rows x 128B per kstep)
    f16x8 af[4];
    {
        const float4* Xr = (const float4*)(X + (size_t)rowc * 128);
#pragma unroll
        for (int kk = 0; kk < 4; ++kk) {
            float4 va = Xr[kk * 8 + hi * 2];
            float4 vb = Xr[kk * 8 + hi * 2 + 1];
            f16x8 a;
            a[0] = (_Float16)va.x; a[1] = (_Float16)va.y;
            a[2] = (_Float16)va.z; a[3] = (_Float16)va.w;
            a[4] = (_Float16)vb.x; a[5] = (_Float16)vb.y;
            a[6] = (_Float16)vb.z; a[7] = (_Float16)vb.w;
            af[kk] = a;
        }
    }

    // alpha coefficients for this lane's columns (col = ct*16 + c16)
    float asv[8], adv[8];
#pragma unroll
    for (int ct = 0; ct < 8; ++ct) {
        asv[ct] = a_src[ct * 16 + c16];
        adv[ct] = a_dst[ct * 16 + c16];
    }

    __syncthreads();

    float psum_s[2][4] = {{0.f,0.f,0.f,0.f},{0.f,0.f,0.f,0.f}};
    float psum_d[2][4] = {{0.f,0.f,0.f,0.f},{0.f,0.f,0.f,0.f}};

#pragma unroll
    for (int ct = 0; ct < 8; ++ct) {
        int col = ct * 16 + c16;
        int cswz = (col & 7) << 4;
        f32x4 acc = {0.f, 0.f, 0.f, 0.f};
#pragma unroll
        for (int kk = 0; kk < 4; ++kk) {
            int byte = ((col << 8) + (kk << 6) + (hi << 4)) ^ cswz;
            f16x8 bf = *(const f16x8*)(wsm + byte);
            acc = __builtin_amdgcn_mfma_f32_16x16x32_f16(af[kk], bf, acc, 0, 0, 0);
        }
        int head = ct >> 2;
#pragma unroll
        for (int reg = 0; reg < 4; ++reg) {
            int row = rowBase + hi * 4 + reg;
            float v = acc[reg];
            if (row < n)
                Hh[(size_t)row * 128 + col] = (_Float16)v;
            psum_s[head][reg] += v * asv[ct];
            psum_d[head][reg] += v * adv[ct];
        }
    }

    // reduce alpha partials over the 16 lanes sharing each row (width-16)
#pragma unroll
    for (int head = 0; head < 2; ++head) {
#pragma unroll
        for (int reg = 0; reg < 4; ++reg) {
            float ps = psum_s[head][reg];
            float pd = psum_d[head][reg];
#pragma unroll
            for (int m = 8; m >= 1; m >>= 1) {
                ps += __shfl_xor(ps, m, 16);
                pd += __shfl_xor(pd, m, 16);
            }
            if (c16 == 0) {
                int row = rowBase + hi * 4 + reg;
                if (row < n) {
                    as_out[row * 2 + head] = ps;
                    ad_out[row * 2 + head] = pd;
                }
            }
        }
    }
}

// Aggregation v2: one wave per node. Lane c owns channels (2c,2c+1); head=c>>5.
// Phase A: edge weights lane-parallel into LDS. Phase B: replay, 8-deep.
__global__ __launch_bounds__(256) void k_agg(
    const _Float16* __restrict__ Hh, const float* __restrict__ as,
    const float* __restrict__ ad, const float* __restrict__ bias,
    const int* __restrict__ csr, const int* __restrict__ off,
    const int* __restrict__ deg, float* __restrict__ out, int n) {
    __shared__ int4 swbuf[4][64];               // 4 KB: per-wave edge packets
    int wave = threadIdx.x >> 6, lane = threadIdx.x & 63;
    int node = blockIdx.x * 4 + wave;
    if (node >= n) return;
    int o = off[node], d = deg[node];
    int head = lane >> 5;
    f32x2 adp = *(const f32x2*)(ad + (size_t)node * 2);
    const _Float16* Hl = Hh + 2 * lane;         // lane-fixed channel offset
    float acc0 = 0.f, acc1 = 0.f, den0 = 0.f, den1 = 0.f;

    for (int base = 0; base < d; base += 64) {
        int rem = d - base;
        // ---- phase A: lane j handles edge base+j ----
        int jj = lane < rem ? lane : (rem - 1);
        int s = csr[o + base + jj];
        f32x2 a2 = *(const f32x2*)(as + (size_t)s * 2);
        float e0 = a2.x + adp.x; e0 = fmaxf(e0, 0.2f * e0);
        float e1 = a2.y + adp.y; e1 = fmaxf(e1, 0.2f * e1);
        float w0 = __expf(e0), w1 = __expf(e1);
        if (lane >= rem) { w0 = 0.f; w1 = 0.f; }
        den0 += w0; den1 += w1;
        int4 pk;
        pk.x = s; pk.y = __float_as_int(w0); pk.z = __float_as_int(w1); pk.w = 0;
        swbuf[wave][lane] = pk;                 // in-wave producer/consumer

        // ---- phase B: replay m edges, 8 gather chains in flight ----
        int m = rem < 64 ? rem : 64;
        int j = 0;
        for (; j + 8 <= m; j += 8) {
            int4 p0 = swbuf[wave][j + 0];
            int4 p1 = swbuf[wave][j + 1];
            int4 p2 = swbuf[wave][j + 2];
            int4 p3 = swbuf[wave][j + 3];
            int4 p4 = swbuf[wave][j + 4];
            int4 p5 = swbuf[wave][j + 5];
            int4 p6 = swbuf[wave][j + 6];
            int4 p7 = swbuf[wave][j + 7];
            h2v g0 = *(const h2v*)(Hl + (size_t)p0.x * 128);
            h2v g1 = *(const h2v*)(Hl + (size_t)p1.x * 128);
            h2v g2 = *(const h2v*)(Hl + (size_t)p2.x * 128);
            h2v g3 = *(const h2v*)(Hl + (size_t)p3.x * 128);
            h2v g4 = *(const h2v*)(Hl + (size_t)p4.x * 128);
            h2v g5 = *(const h2v*)(Hl + (size_t)p5.x * 128);
            h2v g6 = *(const h2v*)(Hl + (size_t)p6.x * 128);
            h2v g7 = *(const h2v*)(Hl + (size_t)p7.x * 128);
            float w0_ = __int_as_float(head ? p0.z : p0.y);
            float w1_ = __int_as_float(head ? p1.z : p1.y);
            float w2_ = __int_as_float(head ? p2.z : p2.y);
            float w3_ = __int_as_float(head ? p3.z : p3.y);
            float w4_ = __int_as_float(head ? p4.z : p4.y);
            float w5_ = __int_as_float(head ? p5.z : p5.y);
            float w6_ = __int_as_float(head ? p6.z : p6.y);
            float w7_ = __int_as_float(head ? p7.z : p7.y);
            acc0 += w0_ * (float)g0.x; acc1 += w0_ * (float)g0.y;
            acc0 += w1_ * (float)g1.x; acc1 += w1_ * (float)g1.y;
            acc0 += w2_ * (float)g2.x; acc1 += w2_ * (float)g2.y;
            acc0 += w3_ * (float)g3.x; acc1 += w3_ * (float)g3.y;
            acc0 += w4_ * (float)g4.x; acc1 += w4_ * (float)g4.y;
            acc0 += w5_ * (float)g5.x; acc1 += w5_ * (float)g5.y;
            acc0 += w6_ * (float)g6.x; acc1 += w6_ * (float)g6.y;
            acc0 += w7_ * (float)g7.x; acc1 += w7_ * (float)g7.y;
        }
        for (; j + 4 <= m; j += 4) {
            int4 p0 = swbuf[wave][j + 0];
            int4 p1 = swbuf[wave][j + 1];
            int4 p2 = swbuf[wave][j + 2];
            int4 p3 = swbuf[wave][j + 3];
            h2v g0 = *(const h2v*)(Hl + (size_t)p0.x * 128);
            h2v g1 = *(const h2v*)(Hl + (size_t)p1.x * 128);
            h2v g2 = *(const h2v*)(Hl + (size_t)p2.x * 128);
            h2v g3 = *(const h2v*)(Hl + (size_t)p3.x * 128);
            float w0_ = __int_as_float(head ? p0.z : p0.y);
            float w1_ = __int_as_float(head ? p1.z : p1.y);
            float w2_ = __int_as_float(head ? p2.z : p2.y);
            float w3_ = __int_as_float(head ? p3.z : p3.y);
            acc0 += w0_ * (float)g0.x; acc1 += w0_ * (float)g0.y;
            acc0 += w1_ * (float)g1.x; acc1 += w1_ * (float)g1.y;
            acc0 += w2_ * (float)g2.x; acc1 += w2_ * (float)g2.y;
            acc0 += w3_ * (float)g3.x; acc1 += w3_ * (float)g3.y;
        }
        for (; j < m; ++j) {
            int4 p = swbuf[wave][j];
            h2v g = *(const h2v*)(Hl + (size_t)p.x * 128);
            float w = __int_as_float(head ? p.z : p.y);
            acc0 += w * (float)g.x; acc1 += w * (float)g.y;
        }
    }

    // reduce denominators across the wave (each lane holds partial sums)
#pragma unroll
    for (int mk = 1; mk < 64; mk <<= 1) {
        den0 += __shfl_xor(den0, mk, 64);
        den1 += __shfl_xor(den1, mk, 64);
    }
    float den = head ? den1 : den0;

    f32x2 b2 = *(const f32x2*)(bias + 2 * lane);
    float inv = 1.f / den;
    float r0 = acc0 * inv + b2.x;
    float r1 = acc1 * inv + b2.y;
    r0 = r0 > 0.f ? r0 : __expf(r0) - 1.f;   // ELU
    r1 = r1 > 0.f ? r1 : __expf(r1) - 1.f;
    f32x2 r; r.x = r0; r.y = r1;
    __builtin_nontemporal_store(r, (f32x2*)(out + (size_t)node * 128 + 2 * lane));
}

extern "C" void kernel_launch(void* const* d_in, const int* in_sizes, int n_in,
                              void* d_out, int out_size, void* d_ws, size_t ws_size,
                              hipStream_t stream) {
    const float* x   = (const float*)d_in[0];
    const int*   ei  = (const int*)d_in[1];
    const float* W1  = (const float*)d_in[2];
    const float* as1 = (const float*)d_in[3];
    const float* ad1 = (const float*)d_in[4];
    const float* b1  = (const float*)d_in[5];
    const float* W2  = (const float*)d_in[6];
    const float* as2 = (const float*)d_in[7];
    const float* ad2 = (const float*)d_in[8];
    const float* b2  = (const float*)d_in[9];

    const int N = in_sizes[0] / 128;
    const int E = in_sizes[1] / 2;

    // workspace carve-up
    _Float16* Hh    = (_Float16*)d_ws;                      // N*128 fp16
    float*  y1      = (float*)(Hh + (size_t)N * 128);       // N*128 fp32
    float*  alpha_s = y1 + (size_t)N * 128;                 // 2N
    float*  alpha_d = alpha_s + 2 * (size_t)N;              // 2N
    int*    deg     = (int*)(alpha_d + 2 * (size_t)N);
    int*    off     = deg + N;
    int*    bsum    = off + N;                              // 128
    int*    csr     = bsum + 128;                           // E+N
    char*   Wt1     = (char*)(csr + E + N);                 // 32 KB
    char*   Wt2     = Wt1 + 32768;                          // 32 KB
    // pos/pos_self alias y1: only live between k_hist and k_scatter,
    // both complete before layer-1 k_agg writes y1.
    int*    pos      = (int*)y1;                            // E
    int*    pos_self = pos + E;                             // N

    hipMemsetAsync(deg, 0, (size_t)N * 4, stream);

    int nb = (N + 1023) / 1024;
    k_wprep<<<64, 256, 0, stream>>>(W1, W2, Wt1, Wt2);
    k_hist<<<((E >> 2) + N + 255) / 256, 256, 0, stream>>>(ei, deg, pos, pos_self, E, N);
    k_scan_block<<<nb, 1024, 0, stream>>>(deg, off, bsum, N);
    k_scan_bsum<<<1, 128, 0, stream>>>(bsum, nb);
    k_scan_add<<<nb, 1024, 0, stream>>>(off, bsum, N);
    k_scatter<<<((E >> 2) + N + 255) / 256, 256, 0, stream>>>(ei, off, pos, pos_self, csr, E, N);

    // layer 1
    k_gemm_alpha<<<(N + 63) / 64, 256, 0, stream>>>(x, Wt1, as1, ad1, Hh, alpha_s, alpha_d, N);
    k_agg<<<(N + 3) / 4, 256, 0, stream>>>(Hh, alpha_s, alpha_d, b1, csr, off, deg, y1, N);

    // layer 2
    k_gemm_alpha<<<(N + 63) / 64, 256, 0, stream>>>(y1, Wt2, as2, ad2, Hh, alpha_s, alpha_d, N);
    k_agg<<<(N + 3) / 4, 256, 0, stream>>>(Hh, alpha_s, alpha_d, b2, csr, off, deg, (float*)d_out, N);
}